// Round 8
// baseline (190.470 us; speedup 1.0000x reference)
//
#include <hip/hip_runtime.h>

// ---------------------------------------------------------------------------
// T5Attention forward: out = (softmax(Q K^T + bias) V) Wo
// B=2, S=2048, D=1024, H=16, DK=64, buckets=32, max_dist=128
// bf16 MFMA (16x16x32), fp32 accumulate.
// r8 = r7 (passed) with k_attn occupancy fix ONLY:
//   - 8 waves/block (512 thr), each wave = the same proven QBLK=16 path
//   - grid 512, chunked XCD map (4 planes/XCD)
//   - staging split across 8 waves (1 K + 1 V gload16 per wave)
//   - __launch_bounds__(512, 8) to cap VGPR at 64 (8 waves/SIMD)
// ---------------------------------------------------------------------------

typedef __attribute__((ext_vector_type(8)))  unsigned short u16x8;
typedef __attribute__((ext_vector_type(4)))  unsigned short u16x4;
typedef __attribute__((ext_vector_type(8)))  __bf16         bf16x8;
typedef __attribute__((ext_vector_type(4)))  float          f32x4;
typedef __attribute__((ext_vector_type(4)))  unsigned int   u32x4;

#define GLOBAL_AS __attribute__((address_space(1)))
#define LDS_AS    __attribute__((address_space(3)))

static __device__ inline f32x4 MFMA(u16x8 a, u16x8 b, f32x4 c) {
  return __builtin_amdgcn_mfma_f32_16x16x32_bf16(
      __builtin_bit_cast(bf16x8, a), __builtin_bit_cast(bf16x8, b), c, 0, 0, 0);
}

static __device__ inline void gload16(const void* g, void* l) {
  __builtin_amdgcn_global_load_lds((const GLOBAL_AS unsigned int*)g,
                                   (LDS_AS unsigned int*)l, 16, 0, 0);
}

// float -> bf16 bits, round-to-nearest-even
static __device__ inline unsigned short f2bf(float x) {
  unsigned int u = __builtin_bit_cast(unsigned int, x);
  u = (u + 0x7FFFu + ((u >> 16) & 1u)) >> 16;
  return (unsigned short)u;
}

// packed f32x2 -> bf16x2, one instruction
static __device__ inline unsigned int cvtpk(float lo, float hi) {
  unsigned int r;
  asm volatile("v_cvt_pk_bf16_f32 %0, %1, %2" : "=v"(r) : "v"(lo), "v"(hi));
  return r;
}

#define L2E 1.4426950408889634f

// ---------------------------------------------------------------------------
// prep: fp32 -> bf16 convert (vectorized)
__global__ void k_cvt(const float* __restrict__ src, unsigned short* __restrict__ dst, int n4) {
  int i = blockIdx.x * blockDim.x + threadIdx.x;
  if (i >= n4) return;
  float4 v = *(const float4*)(src + (size_t)i * 4);
  u16x4 o;
  o[0] = f2bf(v.x); o[1] = f2bf(v.y); o[2] = f2bf(v.z); o[3] = f2bf(v.w);
  *(u16x4*)(dst + (size_t)i * 4) = o;
}

// prep: transpose+convert  src fp32 [K][N] row-major -> dst bf16 [N][K] row-major
__global__ __launch_bounds__(256) void k_tc(const float* __restrict__ src,
                                            unsigned short* __restrict__ dst,
                                            int K, int N) {
  __shared__ float tile[64][65];
  int k0 = blockIdx.y << 6, n0 = blockIdx.x << 6;
  int t = threadIdx.x;
  int rr = t >> 4, cc = (t & 15) << 2;
#pragma unroll
  for (int j = 0; j < 4; j++) {
    float4 v = *(const float4*)(src + (size_t)(k0 + rr + j * 16) * N + n0 + cc);
    tile[rr + j * 16][cc + 0] = v.x;
    tile[rr + j * 16][cc + 1] = v.y;
    tile[rr + j * 16][cc + 2] = v.z;
    tile[rr + j * 16][cc + 3] = v.w;
  }
  __syncthreads();
#pragma unroll
  for (int j = 0; j < 4; j++) {
    int n = rr + j * 16;
    u16x4 o;
    o[0] = f2bf(tile[cc + 0][n]);
    o[1] = f2bf(tile[cc + 1][n]);
    o[2] = f2bf(tile[cc + 2][n]);
    o[3] = f2bf(tile[cc + 3][n]);
    *(u16x4*)(dst + (size_t)(n0 + n) * K + k0 + cc) = o;
  }
}

// prep: bias table (pre-scaled by log2e)
// btab[h*4095 + (rel_pos+2047)] = rel_emb[bucket(rel_pos)][h] * L2E
__global__ void k_bias(const float* __restrict__ rel_emb, float* __restrict__ btab) {
  int i = blockIdx.x * blockDim.x + threadIdx.x;
  if (i >= 16 * 4095) return;
  int h = i / 4095;
  int rp = i % 4095 - 2047;
  int rb = rp > 0 ? 16 : 0;
  int arp = rp < 0 ? -rp : rp;
  int v;
  if (arp < 8) {
    v = arp;
  } else {
    float t = logf((float)arp * 0.125f);
    t = t / 2.772588722239781f;
    t = t * 8.0f;
    v = 8 + (int)t;
    if (v > 15) v = 15;
  }
  btab[i] = rel_emb[(rb + v) * 16 + h] * L2E;
}

// ---------------------------------------------------------------------------
// GEMM: C[M,N] = A[M,K](bf16) * Bt[N,K](bf16, pre-transposed)
// EPI=0: scatter into qkv planes; Q scaled by log2e; V written TRANSPOSED
//        ([plane][d][s]). EPI=1: fp32 row-major out.
template <int EPI>
__global__ __launch_bounds__(256) void k_gemm(const unsigned short* __restrict__ A,
                                              const unsigned short* __restrict__ Bt,
                                              void* __restrict__ outp,
                                              int M, int N, int K) {
  __shared__ __attribute__((aligned(16))) char smem[32768];
  const int tid = threadIdx.x;
  const int lane = tid & 63, w = tid >> 6;
  const int l15 = lane & 15, g = lane >> 4;
  const int wr = w >> 1, wc = w & 1;
  const int bm0 = blockIdx.y << 7, bn0 = blockIdx.x << 7;

  const char* Ag = (const char*)A + (size_t)bm0 * K * 2;
  const char* Bg = (const char*)Bt + (size_t)bn0 * K * 2;

  f32x4 acc[4][4];
#pragma unroll
  for (int i = 0; i < 4; i++)
#pragma unroll
    for (int j = 0; j < 4; j++) acc[i][j] = (f32x4)0.0f;

  const int rowA = wr * 64 + l15;
  const int rowB = wc * 64 + l15;
  const int swz = (l15 & 7) << 4;

  for (int kt = 0; kt < K; kt += 64) {
#pragma unroll
    for (int j = 0; j < 4; j++) {
      int idx = ((j * 4 + w) << 10) + (lane << 4);
      int row = idx >> 7;
      int gs = (idx >> 4) & 7;
      size_t co = (size_t)row * (K * 2) + kt * 2 + ((gs ^ (row & 7)) << 4);
      gload16(Ag + co, smem + ((j * 4 + w) << 10));
      gload16(Bg + co, smem + 16384 + ((j * 4 + w) << 10));
    }
    __syncthreads();
#pragma unroll
    for (int kk = 0; kk < 2; kk++) {
      const int cp = ((kk << 6) + (g << 4)) ^ swz;
      u16x8 af[4], bfv[4];
#pragma unroll
      for (int mt = 0; mt < 4; mt++)
        af[mt] = *(const u16x8*)(smem + ((rowA + mt * 16) << 7) + cp);
#pragma unroll
      for (int nt = 0; nt < 4; nt++)
        bfv[nt] = *(const u16x8*)(smem + 16384 + ((rowB + nt * 16) << 7) + cp);
#pragma unroll
      for (int mt = 0; mt < 4; mt++)
#pragma unroll
        for (int nt = 0; nt < 4; nt++)
          acc[mt][nt] = MFMA(af[mt], bfv[nt], acc[mt][nt]);
    }
    __syncthreads();
  }

#pragma unroll
  for (int mt = 0; mt < 4; mt++) {
#pragma unroll
    for (int nt = 0; nt < 4; nt++) {
#pragma unroll
      for (int r = 0; r < 4; r++) {
        int m = bm0 + wr * 64 + mt * 16 + g * 4 + r;
        int n = bn0 + wc * 64 + nt * 16 + l15;
        float val = acc[mt][nt][r];
        if (EPI == 0) {
          int which = n >> 10;
          int hh = (n >> 6) & 15;
          int d = n & 63;
          int bb = m >> 11, s = m & 2047;
          int plane = bb * 16 + hh;
          unsigned short* o = (unsigned short*)outp;
          if (which == 0) {        // Q, pre-scaled by log2e
            o[(size_t)plane * 131072 + (size_t)s * 64 + d] = f2bf(val * L2E);
          } else if (which == 1) { // K
            o[4194304 + (size_t)plane * 131072 + (size_t)s * 64 + d] = f2bf(val);
          } else {                 // V^T: [plane][d][s]
            o[8388608 + (size_t)plane * 131072 + (size_t)d * 2048 + s] = f2bf(val);
          }
        } else {
          ((float*)outp)[(size_t)m * N + n] = val;
        }
      }
    }
  }
}

// ---------------------------------------------------------------------------
// Flash attention — r7 per-wave code EXACTLY; 8 waves/block, grid 512.
__global__ __launch_bounds__(512, 8) void k_attn(const unsigned short* __restrict__ qkv,
                                                 const float* __restrict__ btab,
                                                 unsigned short* __restrict__ ctx) {
  __shared__ __attribute__((aligned(16))) char smem[32768]; // 2 bufs x (K 8K + V 8K)
  const int tid = threadIdx.x;
  const int lane = tid & 63, w = tid >> 6;      // w in [0,8)
  const int l15 = lane & 15, g = lane >> 4;

  // chunked XCD map: each XCD gets 4 consecutive planes
  const int wg = ((blockIdx.x & 7) << 6) + (blockIdx.x >> 3);
  const int plane = wg >> 4, qb = wg & 15;
  const int h = plane & 15, b = plane >> 4;
  const int q0 = (qb << 7) + (w << 4);          // block: 128 q rows, wave: 16

  const unsigned short* Qp = qkv + (size_t)plane * 131072;
  const unsigned short* Kp = qkv + 4194304 + (size_t)plane * 131072;
  const unsigned short* Vt = qkv + 8388608 + (size_t)plane * 131072;

  u16x8 qa[2];
#pragma unroll
  for (int kk = 0; kk < 2; kk++)
    qa[kk] = *(const u16x8*)(Qp + (size_t)(q0 + l15) * 64 + kk * 32 + g * 8);

  float m_r = -1e30f;
  f32x4 oacc[4], lacc;
#pragma unroll
  for (int t = 0; t < 4; t++) oacc[t] = (f32x4)0.0f;
  lacc = (f32x4)0.0f;

  const float* brow = btab + h * 4095 + 2047 - q0;
  const float cpos = btab[h * 4095 + 2047 + 1024];
  const float cneg = btab[h * 4095 + 2047 - 1024];

  u16x8 ones;
  {
    u32x4 ov = {0x3F803F80u, 0x3F803F80u, 0x3F803F80u, 0x3F803F80u};
    ones = __builtin_bit_cast(u16x8, ov);
  }

  // staging source addrs (pre-swizzled, linear LDS dest); 8 waves x 1 row-band
  const int srow = (w << 3) + (lane >> 3);   // 0..63
  const int soff = ((lane & 7) ^ (srow & 7)) << 4;
  const char* Ksrc = (const char*)Kp + (size_t)srow * 128 + soff;
  const char* Vsrc = (const char*)Vt + (size_t)srow * 4096 + soff;

  auto STAGE = [&](int t, int bsel) {
    char* sb = smem + (bsel << 14) + (w << 10);
    gload16(Ksrc + (size_t)t * 8192, sb);            // K rows w*8..w*8+7
    gload16(Vsrc + (size_t)t * 128, sb + 8192);      // V^T d rows w*8..w*8+7
  };

  STAGE(0, 0);
  __syncthreads();

  for (int t = 0; t < 32; ++t) {
    const int c = t & 1;
    if (t < 31) STAGE(t + 1, c ^ 1);
    const char* kb = smem + (c << 14);
    const char* vbuf = kb + 8192;
    const int kv = t << 6;

    // S^T = K Q^T : lane holds S^T[key = nt*16 + g*4 + r][q = q0 + l15]
    f32x4 s[4];
    __builtin_amdgcn_s_setprio(1);
#pragma unroll
    for (int nt = 0; nt < 4; nt++) {
      int keyr = nt * 16 + l15;
      int sw = (keyr & 7) << 4;
      u16x8 kb0 = *(const u16x8*)(kb + (keyr << 7) + ((g << 4) ^ sw));
      u16x8 kb1 = *(const u16x8*)(kb + (keyr << 7) + ((64 + (g << 4)) ^ sw));
      f32x4 z = (f32x4)0.0f;
      z = MFMA(kb0, qa[0], z);
      z = MFMA(kb1, qa[1], z);
      s[nt] = z;
    }
    __builtin_amdgcn_s_setprio(0);

    // bias (log2 domain): far tiles have saturated (constant) bucket
    int delta = kv - q0;
    float cb;
    if (delta >= 112 || delta <= -160) {
      cb = delta > 0 ? cpos : cneg;
    } else {
      cb = 0.0f;
      const float* bp = brow + kv + (g << 2) - l15;
#pragma unroll
      for (int nt = 0; nt < 4; nt++)
#pragma unroll
        for (int r = 0; r < 4; r++) s[nt][r] += bp[nt * 16 + r];
    }

    // local max over this lane's 16 scores (partial row max)
    float m1 = fmaxf(fmaxf(s[0][0], s[0][1]), s[0][2]);
    float m2 = fmaxf(fmaxf(s[0][3], s[1][0]), s[1][1]);
    float m3 = fmaxf(fmaxf(s[1][2], s[1][3]), s[2][0]);
    float m4 = fmaxf(fmaxf(s[2][1], s[2][2]), s[2][3]);
    float m5 = fmaxf(fmaxf(s[3][0], s[3][1]), s[3][2]);
    float mloc = fmaxf(fmaxf(fmaxf(m1, m2), fmaxf(m3, m4)), fmaxf(m5, s[3][3]));

    if (!__all(mloc + cb <= m_r + 12.0f)) {   // defer-max (log2 domain)
      float mxrow = fmaxf(mloc, __shfl_xor(mloc, 16));
      mxrow = fmaxf(mxrow, __shfl_xor(mxrow, 32));
      float mnew = fmaxf(m_r, mxrow + cb);
      float alpha = exp2f(m_r - mnew);
      m_r = mnew;
      float a4[4];
#pragma unroll
      for (int r = 0; r < 4; r++) a4[r] = __shfl(alpha, (g << 2) + r);
#pragma unroll
      for (int tt = 0; tt < 4; tt++) {
        f32x4 o = oacc[tt];
        o[0] *= a4[0]; o[1] *= a4[1]; o[2] *= a4[2]; o[3] *= a4[3];
        oacc[tt] = o;
      }
      lacc[0] *= a4[0]; lacc[1] *= a4[1]; lacc[2] *= a4[2]; lacc[3] *= a4[3];
    }

    // P = 2^(s + cb - m), bias (or const) folded into eb
    float eb = cb - m_r;
#pragma unroll
    for (int nt = 0; nt < 4; nt++)
#pragma unroll
      for (int r = 0; r < 4; r++)
        s[nt][r] = __builtin_amdgcn_exp2f(s[nt][r] + eb);

    // pack P -> bf16 pairs, then permlane-swap into PV A-fragments
    unsigned int wpk[4][2];
#pragma unroll
    for (int nt = 0; nt < 4; nt++) {
      wpk[nt][0] = cvtpk(s[nt][0], s[nt][1]);
      wpk[nt][1] = cvtpk(s[nt][2], s[nt][3]);
    }
    u16x8 pa[2];
#pragma unroll
    for (int kk = 0; kk < 2; kk++) {
      unsigned int X0 = wpk[2 * kk][0], Y0 = wpk[2 * kk + 1][0];
      asm volatile("v_permlane32_swap_b32 %0, %1" : "+v"(X0), "+v"(Y0));
      asm volatile("v_permlane16_swap_b32 %0, %1" : "+v"(X0), "+v"(Y0));
      unsigned int X1 = wpk[2 * kk][1], Y1 = wpk[2 * kk + 1][1];
      asm volatile("v_permlane32_swap_b32 %0, %1" : "+v"(X1), "+v"(Y1));
      asm volatile("v_permlane16_swap_b32 %0, %1" : "+v"(X1), "+v"(Y1));
      u32x4 pw = {X0, X1, Y0, Y1};   // words w0,w1,w2,w3
      pa[kk] = __builtin_bit_cast(u16x8, pw);
    }

    // O += P V ; l += P * ones
    __builtin_amdgcn_s_setprio(1);
#pragma unroll
    for (int tt = 0; tt < 4; tt++) {
      int d = tt * 16 + l15;
      int sw = (d & 7) << 4;
      u16x8 vb0 = *(const u16x8*)(vbuf + (d << 7) + ((g << 4) ^ sw));
      u16x8 vb1 = *(const u16x8*)(vbuf + (d << 7) + ((64 + (g << 4)) ^ sw));
      oacc[tt] = MFMA(pa[0], vb0, oacc[tt]);
      oacc[tt] = MFMA(pa[1], vb1, oacc[tt]);
    }
    lacc = MFMA(pa[0], ones, lacc);
    lacc = MFMA(pa[1], ones, lacc);
    __builtin_amdgcn_s_setprio(0);

    __syncthreads();
  }

#pragma unroll
  for (int r = 0; r < 4; r++) {
    float inv = 1.0f / lacc[r];
    size_t rowoff = ((size_t)(b * 2048 + q0 + (g << 2) + r) << 10) + h * 64;
#pragma unroll
    for (int tt = 0; tt < 4; tt++)
      ctx[rowoff + tt * 16 + l15] = f2bf(oacc[tt][r] * inv);
  }
}

// ---------------------------------------------------------------------------
extern "C" void kernel_launch(void* const* d_in, const int* in_sizes, int n_in,
                              void* d_out, int out_size, void* d_ws, size_t ws_size,
                              hipStream_t stream) {
  const float* hs = (const float*)d_in[0];
  const float* wq = (const float*)d_in[1];
  const float* wk = (const float*)d_in[2];
  const float* wv = (const float*)d_in[3];
  const float* wo = (const float*)d_in[4];
  const float* re = (const float*)d_in[5];

  if (ws_size < 50593728u) return;

  char* ws = (char*)d_ws;
  unsigned short* hsb = (unsigned short*)(ws);              // [4096][1024] bf16
  unsigned short* wt  = (unsigned short*)(ws + 8388608);    // [3072][1024] bf16
  unsigned short* wot = (unsigned short*)(ws + 14680064);   // [1024][1024] bf16
  unsigned short* qkv = (unsigned short*)(ws + 16777216);   // q,k [p][s][d]; v^T [p][d][s]
  unsigned short* ctx = (unsigned short*)(ws + 41943040);   // [4096][1024] bf16
  float*          btab = (float*)(ws + 50331648);           // [16][4095] fp32 (x log2e)

  k_cvt<<<4096, 256, 0, stream>>>(hs, hsb, 1048576);
  k_tc<<<dim3(16, 16), 256, 0, stream>>>(wq, wt, 1024, 1024);
  k_tc<<<dim3(16, 16), 256, 0, stream>>>(wk, wt + 1048576, 1024, 1024);
  k_tc<<<dim3(16, 16), 256, 0, stream>>>(wv, wt + 2097152, 1024, 1024);
  k_tc<<<dim3(16, 16), 256, 0, stream>>>(wo, wot, 1024, 1024);
  k_bias<<<256, 256, 0, stream>>>(re, btab);

  k_gemm<0><<<dim3(24, 32), 256, 0, stream>>>(hsb, wt, qkv, 4096, 3072, 1024);
  k_attn<<<512, 512, 0, stream>>>(qkv, btab, ctx);
  k_gemm<1><<<dim3(8, 32), 256, 0, stream>>>(ctx, wot, d_out, 4096, 1024, 1024);
}

// Round 9
// 134.487 us; speedup vs baseline: 1.4163x; 1.4163x over previous
//
#include <hip/hip_runtime.h>

// ---------------------------------------------------------------------------
// T5Attention forward: out = (softmax(Q K^T + bias) V) Wo
// B=2, S=2048, D=1024, H=16, DK=64, buckets=32, max_dist=128
// bf16 MFMA (16x16x32), fp32 accumulate.
// r9 = r8 with the ONLY change: __launch_bounds__(512, 6) (was (512,8) which
//      capped VGPR at 64 -> allocator spilled to scratch, 148MB spill traffic).
//      Cap 85 > natural 68 VGPR -> no spill.
// ---------------------------------------------------------------------------

typedef __attribute__((ext_vector_type(8)))  unsigned short u16x8;
typedef __attribute__((ext_vector_type(4)))  unsigned short u16x4;
typedef __attribute__((ext_vector_type(8)))  __bf16         bf16x8;
typedef __attribute__((ext_vector_type(4)))  float          f32x4;
typedef __attribute__((ext_vector_type(4)))  unsigned int   u32x4;

#define GLOBAL_AS __attribute__((address_space(1)))
#define LDS_AS    __attribute__((address_space(3)))

static __device__ inline f32x4 MFMA(u16x8 a, u16x8 b, f32x4 c) {
  return __builtin_amdgcn_mfma_f32_16x16x32_bf16(
      __builtin_bit_cast(bf16x8, a), __builtin_bit_cast(bf16x8, b), c, 0, 0, 0);
}

static __device__ inline void gload16(const void* g, void* l) {
  __builtin_amdgcn_global_load_lds((const GLOBAL_AS unsigned int*)g,
                                   (LDS_AS unsigned int*)l, 16, 0, 0);
}

// float -> bf16 bits, round-to-nearest-even
static __device__ inline unsigned short f2bf(float x) {
  unsigned int u = __builtin_bit_cast(unsigned int, x);
  u = (u + 0x7FFFu + ((u >> 16) & 1u)) >> 16;
  return (unsigned short)u;
}

// packed f32x2 -> bf16x2, one instruction
static __device__ inline unsigned int cvtpk(float lo, float hi) {
  unsigned int r;
  asm volatile("v_cvt_pk_bf16_f32 %0, %1, %2" : "=v"(r) : "v"(lo), "v"(hi));
  return r;
}

#define L2E 1.4426950408889634f

// ---------------------------------------------------------------------------
// prep: fp32 -> bf16 convert (vectorized)
__global__ void k_cvt(const float* __restrict__ src, unsigned short* __restrict__ dst, int n4) {
  int i = blockIdx.x * blockDim.x + threadIdx.x;
  if (i >= n4) return;
  float4 v = *(const float4*)(src + (size_t)i * 4);
  u16x4 o;
  o[0] = f2bf(v.x); o[1] = f2bf(v.y); o[2] = f2bf(v.z); o[3] = f2bf(v.w);
  *(u16x4*)(dst + (size_t)i * 4) = o;
}

// prep: transpose+convert  src fp32 [K][N] row-major -> dst bf16 [N][K] row-major
__global__ __launch_bounds__(256) void k_tc(const float* __restrict__ src,
                                            unsigned short* __restrict__ dst,
                                            int K, int N) {
  __shared__ float tile[64][65];
  int k0 = blockIdx.y << 6, n0 = blockIdx.x << 6;
  int t = threadIdx.x;
  int rr = t >> 4, cc = (t & 15) << 2;
#pragma unroll
  for (int j = 0; j < 4; j++) {
    float4 v = *(const float4*)(src + (size_t)(k0 + rr + j * 16) * N + n0 + cc);
    tile[rr + j * 16][cc + 0] = v.x;
    tile[rr + j * 16][cc + 1] = v.y;
    tile[rr + j * 16][cc + 2] = v.z;
    tile[rr + j * 16][cc + 3] = v.w;
  }
  __syncthreads();
#pragma unroll
  for (int j = 0; j < 4; j++) {
    int n = rr + j * 16;
    u16x4 o;
    o[0] = f2bf(tile[cc + 0][n]);
    o[1] = f2bf(tile[cc + 1][n]);
    o[2] = f2bf(tile[cc + 2][n]);
    o[3] = f2bf(tile[cc + 3][n]);
    *(u16x4*)(dst + (size_t)(n0 + n) * K + k0 + cc) = o;
  }
}

// prep: bias table (pre-scaled by log2e)
// btab[h*4095 + (rel_pos+2047)] = rel_emb[bucket(rel_pos)][h] * L2E
__global__ void k_bias(const float* __restrict__ rel_emb, float* __restrict__ btab) {
  int i = blockIdx.x * blockDim.x + threadIdx.x;
  if (i >= 16 * 4095) return;
  int h = i / 4095;
  int rp = i % 4095 - 2047;
  int rb = rp > 0 ? 16 : 0;
  int arp = rp < 0 ? -rp : rp;
  int v;
  if (arp < 8) {
    v = arp;
  } else {
    float t = logf((float)arp * 0.125f);
    t = t / 2.772588722239781f;
    t = t * 8.0f;
    v = 8 + (int)t;
    if (v > 15) v = 15;
  }
  btab[i] = rel_emb[(rb + v) * 16 + h] * L2E;
}

// ---------------------------------------------------------------------------
// GEMM: C[M,N] = A[M,K](bf16) * Bt[N,K](bf16, pre-transposed)
// EPI=0: scatter into qkv planes; Q scaled by log2e; V written TRANSPOSED
//        ([plane][d][s]). EPI=1: fp32 row-major out.
template <int EPI>
__global__ __launch_bounds__(256) void k_gemm(const unsigned short* __restrict__ A,
                                              const unsigned short* __restrict__ Bt,
                                              void* __restrict__ outp,
                                              int M, int N, int K) {
  __shared__ __attribute__((aligned(16))) char smem[32768];
  const int tid = threadIdx.x;
  const int lane = tid & 63, w = tid >> 6;
  const int l15 = lane & 15, g = lane >> 4;
  const int wr = w >> 1, wc = w & 1;
  const int bm0 = blockIdx.y << 7, bn0 = blockIdx.x << 7;

  const char* Ag = (const char*)A + (size_t)bm0 * K * 2;
  const char* Bg = (const char*)Bt + (size_t)bn0 * K * 2;

  f32x4 acc[4][4];
#pragma unroll
  for (int i = 0; i < 4; i++)
#pragma unroll
    for (int j = 0; j < 4; j++) acc[i][j] = (f32x4)0.0f;

  const int rowA = wr * 64 + l15;
  const int rowB = wc * 64 + l15;
  const int swz = (l15 & 7) << 4;

  for (int kt = 0; kt < K; kt += 64) {
#pragma unroll
    for (int j = 0; j < 4; j++) {
      int idx = ((j * 4 + w) << 10) + (lane << 4);
      int row = idx >> 7;
      int gs = (idx >> 4) & 7;
      size_t co = (size_t)row * (K * 2) + kt * 2 + ((gs ^ (row & 7)) << 4);
      gload16(Ag + co, smem + ((j * 4 + w) << 10));
      gload16(Bg + co, smem + 16384 + ((j * 4 + w) << 10));
    }
    __syncthreads();
#pragma unroll
    for (int kk = 0; kk < 2; kk++) {
      const int cp = ((kk << 6) + (g << 4)) ^ swz;
      u16x8 af[4], bfv[4];
#pragma unroll
      for (int mt = 0; mt < 4; mt++)
        af[mt] = *(const u16x8*)(smem + ((rowA + mt * 16) << 7) + cp);
#pragma unroll
      for (int nt = 0; nt < 4; nt++)
        bfv[nt] = *(const u16x8*)(smem + 16384 + ((rowB + nt * 16) << 7) + cp);
#pragma unroll
      for (int mt = 0; mt < 4; mt++)
#pragma unroll
        for (int nt = 0; nt < 4; nt++)
          acc[mt][nt] = MFMA(af[mt], bfv[nt], acc[mt][nt]);
    }
    __syncthreads();
  }

#pragma unroll
  for (int mt = 0; mt < 4; mt++) {
#pragma unroll
    for (int nt = 0; nt < 4; nt++) {
#pragma unroll
      for (int r = 0; r < 4; r++) {
        int m = bm0 + wr * 64 + mt * 16 + g * 4 + r;
        int n = bn0 + wc * 64 + nt * 16 + l15;
        float val = acc[mt][nt][r];
        if (EPI == 0) {
          int which = n >> 10;
          int hh = (n >> 6) & 15;
          int d = n & 63;
          int bb = m >> 11, s = m & 2047;
          int plane = bb * 16 + hh;
          unsigned short* o = (unsigned short*)outp;
          if (which == 0) {        // Q, pre-scaled by log2e
            o[(size_t)plane * 131072 + (size_t)s * 64 + d] = f2bf(val * L2E);
          } else if (which == 1) { // K
            o[4194304 + (size_t)plane * 131072 + (size_t)s * 64 + d] = f2bf(val);
          } else {                 // V^T: [plane][d][s]
            o[8388608 + (size_t)plane * 131072 + (size_t)d * 2048 + s] = f2bf(val);
          }
        } else {
          ((float*)outp)[(size_t)m * N + n] = val;
        }
      }
    }
  }
}

// ---------------------------------------------------------------------------
// Flash attention — r7 per-wave code; 8 waves/block, grid 512.
__global__ __launch_bounds__(512, 6) void k_attn(const unsigned short* __restrict__ qkv,
                                                 const float* __restrict__ btab,
                                                 unsigned short* __restrict__ ctx) {
  __shared__ __attribute__((aligned(16))) char smem[32768]; // 2 bufs x (K 8K + V 8K)
  const int tid = threadIdx.x;
  const int lane = tid & 63, w = tid >> 6;      // w in [0,8)
  const int l15 = lane & 15, g = lane >> 4;

  // chunked XCD map: each XCD gets 4 consecutive planes
  const int wg = ((blockIdx.x & 7) << 6) + (blockIdx.x >> 3);
  const int plane = wg >> 4, qb = wg & 15;
  const int h = plane & 15, b = plane >> 4;
  const int q0 = (qb << 7) + (w << 4);          // block: 128 q rows, wave: 16

  const unsigned short* Qp = qkv + (size_t)plane * 131072;
  const unsigned short* Kp = qkv + 4194304 + (size_t)plane * 131072;
  const unsigned short* Vt = qkv + 8388608 + (size_t)plane * 131072;

  u16x8 qa[2];
#pragma unroll
  for (int kk = 0; kk < 2; kk++)
    qa[kk] = *(const u16x8*)(Qp + (size_t)(q0 + l15) * 64 + kk * 32 + g * 8);

  float m_r = -1e30f;
  f32x4 oacc[4], lacc;
#pragma unroll
  for (int t = 0; t < 4; t++) oacc[t] = (f32x4)0.0f;
  lacc = (f32x4)0.0f;

  const float* brow = btab + h * 4095 + 2047 - q0;
  const float cpos = btab[h * 4095 + 2047 + 1024];
  const float cneg = btab[h * 4095 + 2047 - 1024];

  u16x8 ones;
  {
    u32x4 ov = {0x3F803F80u, 0x3F803F80u, 0x3F803F80u, 0x3F803F80u};
    ones = __builtin_bit_cast(u16x8, ov);
  }

  // staging source addrs (pre-swizzled, linear LDS dest); 8 waves x 1 row-band
  const int srow = (w << 3) + (lane >> 3);   // 0..63
  const int soff = ((lane & 7) ^ (srow & 7)) << 4;
  const char* Ksrc = (const char*)Kp + (size_t)srow * 128 + soff;
  const char* Vsrc = (const char*)Vt + (size_t)srow * 4096 + soff;

  auto STAGE = [&](int t, int bsel) {
    char* sb = smem + (bsel << 14) + (w << 10);
    gload16(Ksrc + (size_t)t * 8192, sb);            // K rows w*8..w*8+7
    gload16(Vsrc + (size_t)t * 128, sb + 8192);      // V^T d rows w*8..w*8+7
  };

  STAGE(0, 0);
  __syncthreads();

  for (int t = 0; t < 32; ++t) {
    const int c = t & 1;
    if (t < 31) STAGE(t + 1, c ^ 1);
    const char* kb = smem + (c << 14);
    const char* vbuf = kb + 8192;
    const int kv = t << 6;

    // S^T = K Q^T : lane holds S^T[key = nt*16 + g*4 + r][q = q0 + l15]
    f32x4 s[4];
    __builtin_amdgcn_s_setprio(1);
#pragma unroll
    for (int nt = 0; nt < 4; nt++) {
      int keyr = nt * 16 + l15;
      int sw = (keyr & 7) << 4;
      u16x8 kb0 = *(const u16x8*)(kb + (keyr << 7) + ((g << 4) ^ sw));
      u16x8 kb1 = *(const u16x8*)(kb + (keyr << 7) + ((64 + (g << 4)) ^ sw));
      f32x4 z = (f32x4)0.0f;
      z = MFMA(kb0, qa[0], z);
      z = MFMA(kb1, qa[1], z);
      s[nt] = z;
    }
    __builtin_amdgcn_s_setprio(0);

    // bias (log2 domain): far tiles have saturated (constant) bucket
    int delta = kv - q0;
    float cb;
    if (delta >= 112 || delta <= -160) {
      cb = delta > 0 ? cpos : cneg;
    } else {
      cb = 0.0f;
      const float* bp = brow + kv + (g << 2) - l15;
#pragma unroll
      for (int nt = 0; nt < 4; nt++)
#pragma unroll
        for (int r = 0; r < 4; r++) s[nt][r] += bp[nt * 16 + r];
    }

    // local max over this lane's 16 scores (partial row max)
    float m1 = fmaxf(fmaxf(s[0][0], s[0][1]), s[0][2]);
    float m2 = fmaxf(fmaxf(s[0][3], s[1][0]), s[1][1]);
    float m3 = fmaxf(fmaxf(s[1][2], s[1][3]), s[2][0]);
    float m4 = fmaxf(fmaxf(s[2][1], s[2][2]), s[2][3]);
    float m5 = fmaxf(fmaxf(s[3][0], s[3][1]), s[3][2]);
    float mloc = fmaxf(fmaxf(fmaxf(m1, m2), fmaxf(m3, m4)), fmaxf(m5, s[3][3]));

    if (!__all(mloc + cb <= m_r + 12.0f)) {   // defer-max (log2 domain)
      float mxrow = fmaxf(mloc, __shfl_xor(mloc, 16));
      mxrow = fmaxf(mxrow, __shfl_xor(mxrow, 32));
      float mnew = fmaxf(m_r, mxrow + cb);
      float alpha = exp2f(m_r - mnew);
      m_r = mnew;
      float a4[4];
#pragma unroll
      for (int r = 0; r < 4; r++) a4[r] = __shfl(alpha, (g << 2) + r);
#pragma unroll
      for (int tt = 0; tt < 4; tt++) {
        f32x4 o = oacc[tt];
        o[0] *= a4[0]; o[1] *= a4[1]; o[2] *= a4[2]; o[3] *= a4[3];
        oacc[tt] = o;
      }
      lacc[0] *= a4[0]; lacc[1] *= a4[1]; lacc[2] *= a4[2]; lacc[3] *= a4[3];
    }

    // P = 2^(s + cb - m), bias (or const) folded into eb
    float eb = cb - m_r;
#pragma unroll
    for (int nt = 0; nt < 4; nt++)
#pragma unroll
      for (int r = 0; r < 4; r++)
        s[nt][r] = __builtin_amdgcn_exp2f(s[nt][r] + eb);

    // pack P -> bf16 pairs, then permlane-swap into PV A-fragments
    unsigned int wpk[4][2];
#pragma unroll
    for (int nt = 0; nt < 4; nt++) {
      wpk[nt][0] = cvtpk(s[nt][0], s[nt][1]);
      wpk[nt][1] = cvtpk(s[nt][2], s[nt][3]);
    }
    u16x8 pa[2];
#pragma unroll
    for (int kk = 0; kk < 2; kk++) {
      unsigned int X0 = wpk[2 * kk][0], Y0 = wpk[2 * kk + 1][0];
      asm volatile("v_permlane32_swap_b32 %0, %1" : "+v"(X0), "+v"(Y0));
      asm volatile("v_permlane16_swap_b32 %0, %1" : "+v"(X0), "+v"(Y0));
      unsigned int X1 = wpk[2 * kk][1], Y1 = wpk[2 * kk + 1][1];
      asm volatile("v_permlane32_swap_b32 %0, %1" : "+v"(X1), "+v"(Y1));
      asm volatile("v_permlane16_swap_b32 %0, %1" : "+v"(X1), "+v"(Y1));
      u32x4 pw = {X0, X1, Y0, Y1};   // words w0,w1,w2,w3
      pa[kk] = __builtin_bit_cast(u16x8, pw);
    }

    // O += P V ; l += P * ones
    __builtin_amdgcn_s_setprio(1);
#pragma unroll
    for (int tt = 0; tt < 4; tt++) {
      int d = tt * 16 + l15;
      int sw = (d & 7) << 4;
      u16x8 vb0 = *(const u16x8*)(vbuf + (d << 7) + ((g << 4) ^ sw));
      u16x8 vb1 = *(const u16x8*)(vbuf + (d << 7) + ((64 + (g << 4)) ^ sw));
      oacc[tt] = MFMA(pa[0], vb0, oacc[tt]);
      oacc[tt] = MFMA(pa[1], vb1, oacc[tt]);
    }
    lacc = MFMA(pa[0], ones, lacc);
    lacc = MFMA(pa[1], ones, lacc);
    __builtin_amdgcn_s_setprio(0);

    __syncthreads();
  }

#pragma unroll
  for (int r = 0; r < 4; r++) {
    float inv = 1.0f / lacc[r];
    size_t rowoff = ((size_t)(b * 2048 + q0 + (g << 2) + r) << 10) + h * 64;
#pragma unroll
    for (int tt = 0; tt < 4; tt++)
      ctx[rowoff + tt * 16 + l15] = f2bf(oacc[tt][r] * inv);
  }
}

// ---------------------------------------------------------------------------
extern "C" void kernel_launch(void* const* d_in, const int* in_sizes, int n_in,
                              void* d_out, int out_size, void* d_ws, size_t ws_size,
                              hipStream_t stream) {
  const float* hs = (const float*)d_in[0];
  const float* wq = (const float*)d_in[1];
  const float* wk = (const float*)d_in[2];
  const float* wv = (const float*)d_in[3];
  const float* wo = (const float*)d_in[4];
  const float* re = (const float*)d_in[5];

  if (ws_size < 50593728u) return;

  char* ws = (char*)d_ws;
  unsigned short* hsb = (unsigned short*)(ws);              // [4096][1024] bf16
  unsigned short* wt  = (unsigned short*)(ws + 8388608);    // [3072][1024] bf16
  unsigned short* wot = (unsigned short*)(ws + 14680064);   // [1024][1024] bf16
  unsigned short* qkv = (unsigned short*)(ws + 16777216);   // q,k [p][s][d]; v^T [p][d][s]
  unsigned short* ctx = (unsigned short*)(ws + 41943040);   // [4096][1024] bf16
  float*          btab = (float*)(ws + 50331648);           // [16][4095] fp32 (x log2e)

  k_cvt<<<4096, 256, 0, stream>>>(hs, hsb, 1048576);
  k_tc<<<dim3(16, 16), 256, 0, stream>>>(wq, wt, 1024, 1024);
  k_tc<<<dim3(16, 16), 256, 0, stream>>>(wk, wt + 1048576, 1024, 1024);
  k_tc<<<dim3(16, 16), 256, 0, stream>>>(wv, wt + 2097152, 1024, 1024);
  k_tc<<<dim3(16, 16), 256, 0, stream>>>(wo, wot, 1024, 1024);
  k_bias<<<256, 256, 0, stream>>>(re, btab);

  k_gemm<0><<<dim3(24, 32), 256, 0, stream>>>(hsb, wt, qkv, 4096, 3072, 1024);
  k_attn<<<512, 512, 0, stream>>>(qkv, btab, ctx);
  k_gemm<1><<<dim3(8, 32), 256, 0, stream>>>(ctx, wot, d_out, 4096, 1024, 1024);
}

// Round 10
// 126.308 us; speedup vs baseline: 1.5080x; 1.0648x over previous
//
#include <hip/hip_runtime.h>

// ---------------------------------------------------------------------------
// T5Attention forward: out = (softmax(Q K^T + bias) V) Wo
// B=2, S=2048, D=1024, H=16, DK=64, buckets=32, max_dist=128
// bf16 MFMA (16x16x32), fp32 accumulate.
// r10 = r9 (passed, attn 60us) +
//   (1) attn: 3-buffer pipeline, counted vmcnt(2) BEFORE raw s_barrier,
//       sched_barrier(0) pin; no per-tile vmcnt(0) drain.
//   (2) prep fused into one kernel (cvt + 4x transpose + bias table).
// ---------------------------------------------------------------------------

typedef __attribute__((ext_vector_type(8)))  unsigned short u16x8;
typedef __attribute__((ext_vector_type(4)))  unsigned short u16x4;
typedef __attribute__((ext_vector_type(8)))  __bf16         bf16x8;
typedef __attribute__((ext_vector_type(4)))  float          f32x4;
typedef __attribute__((ext_vector_type(4)))  unsigned int   u32x4;

#define GLOBAL_AS __attribute__((address_space(1)))
#define LDS_AS    __attribute__((address_space(3)))

static __device__ inline f32x4 MFMA(u16x8 a, u16x8 b, f32x4 c) {
  return __builtin_amdgcn_mfma_f32_16x16x32_bf16(
      __builtin_bit_cast(bf16x8, a), __builtin_bit_cast(bf16x8, b), c, 0, 0, 0);
}

static __device__ inline void gload16(const void* g, void* l) {
  __builtin_amdgcn_global_load_lds((const GLOBAL_AS unsigned int*)g,
                                   (LDS_AS unsigned int*)l, 16, 0, 0);
}

// float -> bf16 bits, round-to-nearest-even
static __device__ inline unsigned short f2bf(float x) {
  unsigned int u = __builtin_bit_cast(unsigned int, x);
  u = (u + 0x7FFFu + ((u >> 16) & 1u)) >> 16;
  return (unsigned short)u;
}

// packed f32x2 -> bf16x2, one instruction
static __device__ inline unsigned int cvtpk(float lo, float hi) {
  unsigned int r;
  asm volatile("v_cvt_pk_bf16_f32 %0, %1, %2" : "=v"(r) : "v"(lo), "v"(hi));
  return r;
}

#define L2E 1.4426950408889634f

// ---------------------------------------------------------------------------
// fused prep: blocks [0,4096) cvt hs; [4096,5120) transpose 4 weights;
// [5120,5376) bias table. All independent.
__global__ __launch_bounds__(256) void k_prep(const float* __restrict__ hs,
                                              const float* __restrict__ wq,
                                              const float* __restrict__ wk,
                                              const float* __restrict__ wv,
                                              const float* __restrict__ wo,
                                              const float* __restrict__ re,
                                              unsigned short* __restrict__ hsb,
                                              unsigned short* __restrict__ wt,
                                              unsigned short* __restrict__ wot,
                                              float* __restrict__ btab) {
  __shared__ float tile[64][65];
  const int bid = blockIdx.x;
  const int t = threadIdx.x;

  if (bid < 4096) {              // ---- fp32 -> bf16 convert of hidden_states
    int i = bid * 256 + t;
    float4 v = *(const float4*)(hs + (size_t)i * 4);
    u16x4 o;
    o[0] = f2bf(v.x); o[1] = f2bf(v.y); o[2] = f2bf(v.z); o[3] = f2bf(v.w);
    *(u16x4*)(hsb + (size_t)i * 4) = o;
  } else if (bid < 5120) {       // ---- transpose+convert one 64x64 tile
    int sub = bid - 4096;
    int which = sub >> 8;        // 0=wq 1=wk 2=wv 3=wo
    int sb = sub & 255;
    int n0 = (sb & 15) << 6, k0 = (sb >> 4) << 6;
    const float* src = which == 0 ? wq : which == 1 ? wk : which == 2 ? wv : wo;
    unsigned short* dst = which == 0 ? wt
                        : which == 1 ? wt + 1048576
                        : which == 2 ? wt + 2097152 : wot;
    const int K = 1024, N = 1024;
    int rr = t >> 4, cc = (t & 15) << 2;
#pragma unroll
    for (int j = 0; j < 4; j++) {
      float4 v = *(const float4*)(src + (size_t)(k0 + rr + j * 16) * N + n0 + cc);
      tile[rr + j * 16][cc + 0] = v.x;
      tile[rr + j * 16][cc + 1] = v.y;
      tile[rr + j * 16][cc + 2] = v.z;
      tile[rr + j * 16][cc + 3] = v.w;
    }
    __syncthreads();
#pragma unroll
    for (int j = 0; j < 4; j++) {
      int n = rr + j * 16;
      u16x4 o;
      o[0] = f2bf(tile[cc + 0][n]);
      o[1] = f2bf(tile[cc + 1][n]);
      o[2] = f2bf(tile[cc + 2][n]);
      o[3] = f2bf(tile[cc + 3][n]);
      *(u16x4*)(dst + (size_t)(n0 + n) * K + k0 + cc) = o;
    }
  } else {                       // ---- bias table (pre-scaled by log2e)
    int i = (bid - 5120) * 256 + t;
    if (i < 16 * 4095) {
      int h = i / 4095;
      int rp = i % 4095 - 2047;
      int rb = rp > 0 ? 16 : 0;
      int arp = rp < 0 ? -rp : rp;
      int v;
      if (arp < 8) {
        v = arp;
      } else {
        float tt = logf((float)arp * 0.125f);
        tt = tt / 2.772588722239781f;
        tt = tt * 8.0f;
        v = 8 + (int)tt;
        if (v > 15) v = 15;
      }
      btab[i] = re[(rb + v) * 16 + h] * L2E;
    }
  }
}

// ---------------------------------------------------------------------------
// GEMM: C[M,N] = A[M,K](bf16) * Bt[N,K](bf16, pre-transposed)
// EPI=0: scatter into qkv planes; Q scaled by log2e; V written TRANSPOSED
//        ([plane][d][s]). EPI=1: fp32 row-major out.
template <int EPI>
__global__ __launch_bounds__(256) void k_gemm(const unsigned short* __restrict__ A,
                                              const unsigned short* __restrict__ Bt,
                                              void* __restrict__ outp,
                                              int M, int N, int K) {
  __shared__ __attribute__((aligned(16))) char smem[32768];
  const int tid = threadIdx.x;
  const int lane = tid & 63, w = tid >> 6;
  const int l15 = lane & 15, g = lane >> 4;
  const int wr = w >> 1, wc = w & 1;
  const int bm0 = blockIdx.y << 7, bn0 = blockIdx.x << 7;

  const char* Ag = (const char*)A + (size_t)bm0 * K * 2;
  const char* Bg = (const char*)Bt + (size_t)bn0 * K * 2;

  f32x4 acc[4][4];
#pragma unroll
  for (int i = 0; i < 4; i++)
#pragma unroll
    for (int j = 0; j < 4; j++) acc[i][j] = (f32x4)0.0f;

  const int rowA = wr * 64 + l15;
  const int rowB = wc * 64 + l15;
  const int swz = (l15 & 7) << 4;

  for (int kt = 0; kt < K; kt += 64) {
#pragma unroll
    for (int j = 0; j < 4; j++) {
      int idx = ((j * 4 + w) << 10) + (lane << 4);
      int row = idx >> 7;
      int gs = (idx >> 4) & 7;
      size_t co = (size_t)row * (K * 2) + kt * 2 + ((gs ^ (row & 7)) << 4);
      gload16(Ag + co, smem + ((j * 4 + w) << 10));
      gload16(Bg + co, smem + 16384 + ((j * 4 + w) << 10));
    }
    __syncthreads();
#pragma unroll
    for (int kk = 0; kk < 2; kk++) {
      const int cp = ((kk << 6) + (g << 4)) ^ swz;
      u16x8 af[4], bfv[4];
#pragma unroll
      for (int mt = 0; mt < 4; mt++)
        af[mt] = *(const u16x8*)(smem + ((rowA + mt * 16) << 7) + cp);
#pragma unroll
      for (int nt = 0; nt < 4; nt++)
        bfv[nt] = *(const u16x8*)(smem + 16384 + ((rowB + nt * 16) << 7) + cp);
#pragma unroll
      for (int mt = 0; mt < 4; mt++)
#pragma unroll
        for (int nt = 0; nt < 4; nt++)
          acc[mt][nt] = MFMA(af[mt], bfv[nt], acc[mt][nt]);
    }
    __syncthreads();
  }

#pragma unroll
  for (int mt = 0; mt < 4; mt++) {
#pragma unroll
    for (int nt = 0; nt < 4; nt++) {
#pragma unroll
      for (int r = 0; r < 4; r++) {
        int m = bm0 + wr * 64 + mt * 16 + g * 4 + r;
        int n = bn0 + wc * 64 + nt * 16 + l15;
        float val = acc[mt][nt][r];
        if (EPI == 0) {
          int which = n >> 10;
          int hh = (n >> 6) & 15;
          int d = n & 63;
          int bb = m >> 11, s = m & 2047;
          int plane = bb * 16 + hh;
          unsigned short* o = (unsigned short*)outp;
          if (which == 0) {        // Q, pre-scaled by log2e
            o[(size_t)plane * 131072 + (size_t)s * 64 + d] = f2bf(val * L2E);
          } else if (which == 1) { // K
            o[4194304 + (size_t)plane * 131072 + (size_t)s * 64 + d] = f2bf(val);
          } else {                 // V^T: [plane][d][s]
            o[8388608 + (size_t)plane * 131072 + (size_t)d * 2048 + s] = f2bf(val);
          }
        } else {
          ((float*)outp)[(size_t)m * N + n] = val;
        }
      }
    }
  }
}

// ---------------------------------------------------------------------------
// Flash attention — 8 waves/block, grid 512, 3-buffer counted-vmcnt pipeline.
// Invariant: each wave waits vmcnt(2) for ITS OWN stage-t loads BEFORE the
// barrier -> post-barrier all waves' tile-t data complete. STAGE(t+2) reuses
// the buffer read at t-1, protected by the same barrier.
__global__ __launch_bounds__(512, 6) void k_attn(const unsigned short* __restrict__ qkv,
                                                 const float* __restrict__ btab,
                                                 unsigned short* __restrict__ ctx) {
  __shared__ __attribute__((aligned(16))) char smem[49152]; // 3 x (K 8K + V 8K)
  const int tid = threadIdx.x;
  const int lane = tid & 63, w = tid >> 6;      // w in [0,8)
  const int l15 = lane & 15, g = lane >> 4;

  // chunked XCD map: each XCD gets 4 consecutive planes
  const int wg = ((blockIdx.x & 7) << 6) + (blockIdx.x >> 3);
  const int plane = wg >> 4, qb = wg & 15;
  const int h = plane & 15, b = plane >> 4;
  const int q0 = (qb << 7) + (w << 4);          // block: 128 q rows, wave: 16

  const unsigned short* Qp = qkv + (size_t)plane * 131072;
  const unsigned short* Kp = qkv + 4194304 + (size_t)plane * 131072;
  const unsigned short* Vt = qkv + 8388608 + (size_t)plane * 131072;

  u16x8 qa[2];
#pragma unroll
  for (int kk = 0; kk < 2; kk++)
    qa[kk] = *(const u16x8*)(Qp + (size_t)(q0 + l15) * 64 + kk * 32 + g * 8);

  float m_r = -1e30f;
  f32x4 oacc[4], lacc;
#pragma unroll
  for (int t = 0; t < 4; t++) oacc[t] = (f32x4)0.0f;
  lacc = (f32x4)0.0f;

  const float* brow = btab + h * 4095 + 2047 - q0;
  const float cpos = btab[h * 4095 + 2047 + 1024];
  const float cneg = btab[h * 4095 + 2047 - 1024];

  u16x8 ones;
  {
    u32x4 ov = {0x3F803F80u, 0x3F803F80u, 0x3F803F80u, 0x3F803F80u};
    ones = __builtin_bit_cast(u16x8, ov);
  }

  // staging source addrs (pre-swizzled, linear LDS dest); 8 waves x 1 row-band
  const int srow = (w << 3) + (lane >> 3);   // 0..63
  const int soff = ((lane & 7) ^ (srow & 7)) << 4;
  const char* Ksrc = (const char*)Kp + (size_t)srow * 128 + soff;
  const char* Vsrc = (const char*)Vt + (size_t)srow * 4096 + soff;

  auto STAGE = [&](int t, int bsel) {
    char* sb = smem + bsel * 16384 + (w << 10);
    gload16(Ksrc + (size_t)t * 8192, sb);            // K rows w*8..w*8+7
    gload16(Vsrc + (size_t)t * 128, sb + 8192);      // V^T d rows w*8..w*8+7
  };

  STAGE(0, 0);
  STAGE(1, 1);

  int rb = 0, sbn = 2;
  for (int t = 0; t < 32; ++t) {
    if (t < 30) { asm volatile("s_waitcnt vmcnt(2)" ::: "memory"); }
    else        { asm volatile("s_waitcnt vmcnt(0)" ::: "memory"); }
    asm volatile("s_waitcnt lgkmcnt(0)" ::: "memory");
    __builtin_amdgcn_s_barrier();
    __builtin_amdgcn_sched_barrier(0);
    if (t < 30) { STAGE(t + 2, sbn); sbn = (sbn == 2) ? 0 : sbn + 1; }
    const char* kb = smem + rb * 16384;
    const char* vbuf = kb + 8192;
    rb = (rb == 2) ? 0 : rb + 1;
    const int kv = t << 6;

    // S^T = K Q^T : lane holds S^T[key = nt*16 + g*4 + r][q = q0 + l15]
    f32x4 s[4];
    __builtin_amdgcn_s_setprio(1);
#pragma unroll
    for (int nt = 0; nt < 4; nt++) {
      int keyr = nt * 16 + l15;
      int sw = (keyr & 7) << 4;
      u16x8 kb0 = *(const u16x8*)(kb + (keyr << 7) + ((g << 4) ^ sw));
      u16x8 kb1 = *(const u16x8*)(kb + (keyr << 7) + ((64 + (g << 4)) ^ sw));
      f32x4 z = (f32x4)0.0f;
      z = MFMA(kb0, qa[0], z);
      z = MFMA(kb1, qa[1], z);
      s[nt] = z;
    }
    __builtin_amdgcn_s_setprio(0);

    // bias (log2 domain): far tiles have saturated (constant) bucket
    int delta = kv - q0;
    float cb;
    if (delta >= 112 || delta <= -160) {
      cb = delta > 0 ? cpos : cneg;
    } else {
      cb = 0.0f;
      const float* bp = brow + kv + (g << 2) - l15;
#pragma unroll
      for (int nt = 0; nt < 4; nt++)
#pragma unroll
        for (int r = 0; r < 4; r++) s[nt][r] += bp[nt * 16 + r];
    }

    // local max over this lane's 16 scores (partial row max)
    float m1 = fmaxf(fmaxf(s[0][0], s[0][1]), s[0][2]);
    float m2 = fmaxf(fmaxf(s[0][3], s[1][0]), s[1][1]);
    float m3 = fmaxf(fmaxf(s[1][2], s[1][3]), s[2][0]);
    float m4 = fmaxf(fmaxf(s[2][1], s[2][2]), s[2][3]);
    float m5 = fmaxf(fmaxf(s[3][0], s[3][1]), s[3][2]);
    float mloc = fmaxf(fmaxf(fmaxf(m1, m2), fmaxf(m3, m4)), fmaxf(m5, s[3][3]));

    if (!__all(mloc + cb <= m_r + 12.0f)) {   // defer-max (log2 domain)
      float mxrow = fmaxf(mloc, __shfl_xor(mloc, 16));
      mxrow = fmaxf(mxrow, __shfl_xor(mxrow, 32));
      float mnew = fmaxf(m_r, mxrow + cb);
      float alpha = exp2f(m_r - mnew);
      m_r = mnew;
      float a4[4];
#pragma unroll
      for (int r = 0; r < 4; r++) a4[r] = __shfl(alpha, (g << 2) + r);
#pragma unroll
      for (int tt = 0; tt < 4; tt++) {
        f32x4 o = oacc[tt];
        o[0] *= a4[0]; o[1] *= a4[1]; o[2] *= a4[2]; o[3] *= a4[3];
        oacc[tt] = o;
      }
      lacc[0] *= a4[0]; lacc[1] *= a4[1]; lacc[2] *= a4[2]; lacc[3] *= a4[3];
    }

    // P = 2^(s + cb - m), bias (or const) folded into eb
    float eb = cb - m_r;
#pragma unroll
    for (int nt = 0; nt < 4; nt++)
#pragma unroll
      for (int r = 0; r < 4; r++)
        s[nt][r] = __builtin_amdgcn_exp2f(s[nt][r] + eb);

    // pack P -> bf16 pairs, then permlane-swap into PV A-fragments
    unsigned int wpk[4][2];
#pragma unroll
    for (int nt = 0; nt < 4; nt++) {
      wpk[nt][0] = cvtpk(s[nt][0], s[nt][1]);
      wpk[nt][1] = cvtpk(s[nt][2], s[nt][3]);
    }
    u16x8 pa[2];
#pragma unroll
    for (int kk = 0; kk < 2; kk++) {
      unsigned int X0 = wpk[2 * kk][0], Y0 = wpk[2 * kk + 1][0];
      asm volatile("v_permlane32_swap_b32 %0, %1" : "+v"(X0), "+v"(Y0));
      asm volatile("v_permlane16_swap_b32 %0, %1" : "+v"(X0), "+v"(Y0));
      unsigned int X1 = wpk[2 * kk][1], Y1 = wpk[2 * kk + 1][1];
      asm volatile("v_permlane32_swap_b32 %0, %1" : "+v"(X1), "+v"(Y1));
      asm volatile("v_permlane16_swap_b32 %0, %1" : "+v"(X1), "+v"(Y1));
      u32x4 pw = {X0, X1, Y0, Y1};   // words w0,w1,w2,w3
      pa[kk] = __builtin_bit_cast(u16x8, pw);
    }

    // O += P V ; l += P * ones
    __builtin_amdgcn_s_setprio(1);
#pragma unroll
    for (int tt = 0; tt < 4; tt++) {
      int d = tt * 16 + l15;
      int sw = (d & 7) << 4;
      u16x8 vb0 = *(const u16x8*)(vbuf + (d << 7) + ((g << 4) ^ sw));
      u16x8 vb1 = *(const u16x8*)(vbuf + (d << 7) + ((64 + (g << 4)) ^ sw));
      oacc[tt] = MFMA(pa[0], vb0, oacc[tt]);
      oacc[tt] = MFMA(pa[1], vb1, oacc[tt]);
    }
    lacc = MFMA(pa[0], ones, lacc);
    lacc = MFMA(pa[1], ones, lacc);
    __builtin_amdgcn_s_setprio(0);
  }

#pragma unroll
  for (int r = 0; r < 4; r++) {
    float inv = 1.0f / lacc[r];
    size_t rowoff = ((size_t)(b * 2048 + q0 + (g << 2) + r) << 10) + h * 64;
#pragma unroll
    for (int tt = 0; tt < 4; tt++)
      ctx[rowoff + tt * 16 + l15] = f2bf(oacc[tt][r] * inv);
  }
}

// ---------------------------------------------------------------------------
extern "C" void kernel_launch(void* const* d_in, const int* in_sizes, int n_in,
                              void* d_out, int out_size, void* d_ws, size_t ws_size,
                              hipStream_t stream) {
  const float* hs = (const float*)d_in[0];
  const float* wq = (const float*)d_in[1];
  const float* wk = (const float*)d_in[2];
  const float* wv = (const float*)d_in[3];
  const float* wo = (const float*)d_in[4];
  const float* re = (const float*)d_in[5];

  if (ws_size < 50593728u) return;

  char* ws = (char*)d_ws;
  unsigned short* hsb = (unsigned short*)(ws);              // [4096][1024] bf16
  unsigned short* wt  = (unsigned short*)(ws + 8388608);    // [3072][1024] bf16
  unsigned short* wot = (unsigned short*)(ws + 14680064);   // [1024][1024] bf16
  unsigned short* qkv = (unsigned short*)(ws + 16777216);   // q,k [p][s][d]; v^T [p][d][s]
  unsigned short* ctx = (unsigned short*)(ws + 41943040);   // [4096][1024] bf16
  float*          btab = (float*)(ws + 50331648);           // [16][4095] fp32 (x log2e)

  k_prep<<<5376, 256, 0, stream>>>(hs, wq, wk, wv, wo, re, hsb, wt, wot, btab);
  k_gemm<0><<<dim3(24, 32), 256, 0, stream>>>(hsb, wt, qkv, 4096, 3072, 1024);
  k_attn<<<512, 512, 0, stream>>>(qkv, btab, ctx);
  k_gemm<1><<<dim3(8, 32), 256, 0, stream>>>(ctx, wot, d_out, 4096, 1024, 1024);
}

// Round 12
// 123.402 us; speedup vs baseline: 1.5435x; 1.0235x over previous
//
#include <hip/hip_runtime.h>

// ---------------------------------------------------------------------------
// T5Attention forward: out = (softmax(Q K^T + bias) V) Wo
// B=2, S=2048, D=1024, H=16, DK=64, buckets=32, max_dist=128
// bf16 MFMA (16x16x32), fp32 accumulate.
// r12 = r10 (passing) with k_attn barrier halving ONLY:
//   - 4 LDS buffers (16KB each), 2 tiles processed per iteration
//   - tile body = r10's EXACT code, run twice SEQUENTIALLY with
//     sched_barrier(0) between (no dual-live score sets - r4/5/6/11 lesson)
//   - one __syncthreads per 2 tiles (16 barriers vs 32)
// Prep + GEMMs identical to r10.
// ---------------------------------------------------------------------------

typedef __attribute__((ext_vector_type(8)))  unsigned short u16x8;
typedef __attribute__((ext_vector_type(4)))  unsigned short u16x4;
typedef __attribute__((ext_vector_type(8)))  __bf16         bf16x8;
typedef __attribute__((ext_vector_type(4)))  float          f32x4;
typedef __attribute__((ext_vector_type(4)))  unsigned int   u32x4;

#define GLOBAL_AS __attribute__((address_space(1)))
#define LDS_AS    __attribute__((address_space(3)))

static __device__ inline f32x4 MFMA(u16x8 a, u16x8 b, f32x4 c) {
  return __builtin_amdgcn_mfma_f32_16x16x32_bf16(
      __builtin_bit_cast(bf16x8, a), __builtin_bit_cast(bf16x8, b), c, 0, 0, 0);
}

static __device__ inline void gload16(const void* g, void* l) {
  __builtin_amdgcn_global_load_lds((const GLOBAL_AS unsigned int*)g,
                                   (LDS_AS unsigned int*)l, 16, 0, 0);
}

// float -> bf16 bits, round-to-nearest-even
static __device__ inline unsigned short f2bf(float x) {
  unsigned int u = __builtin_bit_cast(unsigned int, x);
  u = (u + 0x7FFFu + ((u >> 16) & 1u)) >> 16;
  return (unsigned short)u;
}

// packed f32x2 -> bf16x2, one instruction
static __device__ inline unsigned int cvtpk(float lo, float hi) {
  unsigned int r;
  asm volatile("v_cvt_pk_bf16_f32 %0, %1, %2" : "=v"(r) : "v"(lo), "v"(hi));
  return r;
}

#define L2E 1.4426950408889634f

// ---------------------------------------------------------------------------
// fused prep: blocks [0,4096) cvt hs; [4096,5120) transpose 4 weights;
// [5120,5376) bias table. All independent.
__global__ __launch_bounds__(256) void k_prep(const float* __restrict__ hs,
                                              const float* __restrict__ wq,
                                              const float* __restrict__ wk,
                                              const float* __restrict__ wv,
                                              const float* __restrict__ wo,
                                              const float* __restrict__ re,
                                              unsigned short* __restrict__ hsb,
                                              unsigned short* __restrict__ wt,
                                              unsigned short* __restrict__ wot,
                                              float* __restrict__ btab) {
  __shared__ float tile[64][65];
  const int bid = blockIdx.x;
  const int t = threadIdx.x;

  if (bid < 4096) {              // ---- fp32 -> bf16 convert of hidden_states
    int i = bid * 256 + t;
    float4 v = *(const float4*)(hs + (size_t)i * 4);
    u16x4 o;
    o[0] = f2bf(v.x); o[1] = f2bf(v.y); o[2] = f2bf(v.z); o[3] = f2bf(v.w);
    *(u16x4*)(hsb + (size_t)i * 4) = o;
  } else if (bid < 5120) {       // ---- transpose+convert one 64x64 tile
    int sub = bid - 4096;
    int which = sub >> 8;        // 0=wq 1=wk 2=wv 3=wo
    int sb = sub & 255;
    int n0 = (sb & 15) << 6, k0 = (sb >> 4) << 6;
    const float* src = which == 0 ? wq : which == 1 ? wk : which == 2 ? wv : wo;
    unsigned short* dst = which == 0 ? wt
                        : which == 1 ? wt + 1048576
                        : which == 2 ? wt + 2097152 : wot;
    const int K = 1024, N = 1024;
    int rr = t >> 4, cc = (t & 15) << 2;
#pragma unroll
    for (int j = 0; j < 4; j++) {
      float4 v = *(const float4*)(src + (size_t)(k0 + rr + j * 16) * N + n0 + cc);
      tile[rr + j * 16][cc + 0] = v.x;
      tile[rr + j * 16][cc + 1] = v.y;
      tile[rr + j * 16][cc + 2] = v.z;
      tile[rr + j * 16][cc + 3] = v.w;
    }
    __syncthreads();
#pragma unroll
    for (int j = 0; j < 4; j++) {
      int n = rr + j * 16;
      u16x4 o;
      o[0] = f2bf(tile[cc + 0][n]);
      o[1] = f2bf(tile[cc + 1][n]);
      o[2] = f2bf(tile[cc + 2][n]);
      o[3] = f2bf(tile[cc + 3][n]);
      *(u16x4*)(dst + (size_t)(n0 + n) * K + k0 + cc) = o;
    }
  } else {                       // ---- bias table (pre-scaled by log2e)
    int i = (bid - 5120) * 256 + t;
    if (i < 16 * 4095) {
      int h = i / 4095;
      int rp = i % 4095 - 2047;
      int rb = rp > 0 ? 16 : 0;
      int arp = rp < 0 ? -rp : rp;
      int v;
      if (arp < 8) {
        v = arp;
      } else {
        float tt = logf((float)arp * 0.125f);
        tt = tt / 2.772588722239781f;
        tt = tt * 8.0f;
        v = 8 + (int)tt;
        if (v > 15) v = 15;
      }
      btab[i] = re[(rb + v) * 16 + h] * L2E;
    }
  }
}

// ---------------------------------------------------------------------------
// GEMM: C[M,N] = A[M,K](bf16) * Bt[N,K](bf16, pre-transposed)
// EPI=0: scatter into qkv planes; Q scaled by log2e; V written TRANSPOSED
//        ([plane][d][s]). EPI=1: fp32 row-major out.
template <int EPI>
__global__ __launch_bounds__(256) void k_gemm(const unsigned short* __restrict__ A,
                                              const unsigned short* __restrict__ Bt,
                                              void* __restrict__ outp,
                                              int M, int N, int K) {
  __shared__ __attribute__((aligned(16))) char smem[32768];
  const int tid = threadIdx.x;
  const int lane = tid & 63, w = tid >> 6;
  const int l15 = lane & 15, g = lane >> 4;
  const int wr = w >> 1, wc = w & 1;
  const int bm0 = blockIdx.y << 7, bn0 = blockIdx.x << 7;

  const char* Ag = (const char*)A + (size_t)bm0 * K * 2;
  const char* Bg = (const char*)Bt + (size_t)bn0 * K * 2;

  f32x4 acc[4][4];
#pragma unroll
  for (int i = 0; i < 4; i++)
#pragma unroll
    for (int j = 0; j < 4; j++) acc[i][j] = (f32x4)0.0f;

  const int rowA = wr * 64 + l15;
  const int rowB = wc * 64 + l15;
  const int swz = (l15 & 7) << 4;

  for (int kt = 0; kt < K; kt += 64) {
#pragma unroll
    for (int j = 0; j < 4; j++) {
      int idx = ((j * 4 + w) << 10) + (lane << 4);
      int row = idx >> 7;
      int gs = (idx >> 4) & 7;
      size_t co = (size_t)row * (K * 2) + kt * 2 + ((gs ^ (row & 7)) << 4);
      gload16(Ag + co, smem + ((j * 4 + w) << 10));
      gload16(Bg + co, smem + 16384 + ((j * 4 + w) << 10));
    }
    __syncthreads();
#pragma unroll
    for (int kk = 0; kk < 2; kk++) {
      const int cp = ((kk << 6) + (g << 4)) ^ swz;
      u16x8 af[4], bfv[4];
#pragma unroll
      for (int mt = 0; mt < 4; mt++)
        af[mt] = *(const u16x8*)(smem + ((rowA + mt * 16) << 7) + cp);
#pragma unroll
      for (int nt = 0; nt < 4; nt++)
        bfv[nt] = *(const u16x8*)(smem + 16384 + ((rowB + nt * 16) << 7) + cp);
#pragma unroll
      for (int mt = 0; mt < 4; mt++)
#pragma unroll
        for (int nt = 0; nt < 4; nt++)
          acc[mt][nt] = MFMA(af[mt], bfv[nt], acc[mt][nt]);
    }
    __syncthreads();
  }

#pragma unroll
  for (int mt = 0; mt < 4; mt++) {
#pragma unroll
    for (int nt = 0; nt < 4; nt++) {
#pragma unroll
      for (int r = 0; r < 4; r++) {
        int m = bm0 + wr * 64 + mt * 16 + g * 4 + r;
        int n = bn0 + wc * 64 + nt * 16 + l15;
        float val = acc[mt][nt][r];
        if (EPI == 0) {
          int which = n >> 10;
          int hh = (n >> 6) & 15;
          int d = n & 63;
          int bb = m >> 11, s = m & 2047;
          int plane = bb * 16 + hh;
          unsigned short* o = (unsigned short*)outp;
          if (which == 0) {        // Q, pre-scaled by log2e
            o[(size_t)plane * 131072 + (size_t)s * 64 + d] = f2bf(val * L2E);
          } else if (which == 1) { // K
            o[4194304 + (size_t)plane * 131072 + (size_t)s * 64 + d] = f2bf(val);
          } else {                 // V^T: [plane][d][s]
            o[8388608 + (size_t)plane * 131072 + (size_t)d * 2048 + s] = f2bf(val);
          }
        } else {
          ((float*)outp)[(size_t)m * N + n] = val;
        }
      }
    }
  }
}

// ---------------------------------------------------------------------------
// Flash attention — 8 waves/block, grid 512. r10's per-tile code run twice
// per iteration (sequentially, sched_barrier(0) between), 4 LDS buffers,
// one __syncthreads per 2 tiles.
__global__ __launch_bounds__(512, 6) void k_attn(const unsigned short* __restrict__ qkv,
                                                 const float* __restrict__ btab,
                                                 unsigned short* __restrict__ ctx) {
  __shared__ __attribute__((aligned(16))) char smem[65536]; // 4 x (K 8K + V 8K)
  const int tid = threadIdx.x;
  const int lane = tid & 63, w = tid >> 6;      // w in [0,8)
  const int l15 = lane & 15, g = lane >> 4;

  // chunked XCD map: each XCD gets 4 consecutive planes
  const int wg = ((blockIdx.x & 7) << 6) + (blockIdx.x >> 3);
  const int plane = wg >> 4, qb = wg & 15;
  const int h = plane & 15, b = plane >> 4;
  const int q0 = (qb << 7) + (w << 4);          // block: 128 q rows, wave: 16

  const unsigned short* Qp = qkv + (size_t)plane * 131072;
  const unsigned short* Kp = qkv + 4194304 + (size_t)plane * 131072;
  const unsigned short* Vt = qkv + 8388608 + (size_t)plane * 131072;

  u16x8 qa[2];
#pragma unroll
  for (int kk = 0; kk < 2; kk++)
    qa[kk] = *(const u16x8*)(Qp + (size_t)(q0 + l15) * 64 + kk * 32 + g * 8);

  float m_r = -1e30f;
  f32x4 oacc[4], lacc;
#pragma unroll
  for (int t = 0; t < 4; t++) oacc[t] = (f32x4)0.0f;
  lacc = (f32x4)0.0f;

  const float* brow = btab + h * 4095 + 2047 - q0;
  const float cpos = btab[h * 4095 + 2047 + 1024];
  const float cneg = btab[h * 4095 + 2047 - 1024];

  u16x8 ones;
  {
    u32x4 ov = {0x3F803F80u, 0x3F803F80u, 0x3F803F80u, 0x3F803F80u};
    ones = __builtin_bit_cast(u16x8, ov);
  }

  // staging source addrs (pre-swizzled, linear LDS dest); 8 waves x 1 row-band
  const int srow = (w << 3) + (lane >> 3);   // 0..63
  const int soff = ((lane & 7) ^ (srow & 7)) << 4;
  const char* Ksrc = (const char*)Kp + (size_t)srow * 128 + soff;
  const char* Vsrc = (const char*)Vt + (size_t)srow * 4096 + soff;

  auto STAGE = [&](int t, int bsel) {
    char* sb = smem + (bsel << 14) + (w << 10);
    gload16(Ksrc + (size_t)t * 8192, sb);            // K rows w*8..w*8+7
    gload16(Vsrc + (size_t)t * 128, sb + 8192);      // V^T d rows w*8..w*8+7
  };

  // ---- one 64-key tile: r10's EXACT body ----
  auto TILE = [&](int t, int bsel) {
    const char* kb = smem + (bsel << 14);
    const char* vbuf = kb + 8192;
    const int kv = t << 6;

    // S^T = K Q^T : lane holds S^T[key = nt*16 + g*4 + r][q = q0 + l15]
    f32x4 s[4];
    __builtin_amdgcn_s_setprio(1);
#pragma unroll
    for (int nt = 0; nt < 4; nt++) {
      int keyr = nt * 16 + l15;
      int sw = (keyr & 7) << 4;
      u16x8 kb0 = *(const u16x8*)(kb + (keyr << 7) + ((g << 4) ^ sw));
      u16x8 kb1 = *(const u16x8*)(kb + (keyr << 7) + ((64 + (g << 4)) ^ sw));
      f32x4 z = (f32x4)0.0f;
      z = MFMA(kb0, qa[0], z);
      z = MFMA(kb1, qa[1], z);
      s[nt] = z;
    }
    __builtin_amdgcn_s_setprio(0);

    // bias (log2 domain): far tiles have saturated (constant) bucket
    int delta = kv - q0;
    float cb;
    if (delta >= 112 || delta <= -160) {
      cb = delta > 0 ? cpos : cneg;
    } else {
      cb = 0.0f;
      const float* bp = brow + kv + (g << 2) - l15;
#pragma unroll
      for (int nt = 0; nt < 4; nt++)
#pragma unroll
        for (int r = 0; r < 4; r++) s[nt][r] += bp[nt * 16 + r];
    }

    // local max over this lane's 16 scores (partial row max)
    float m1 = fmaxf(fmaxf(s[0][0], s[0][1]), s[0][2]);
    float m2 = fmaxf(fmaxf(s[0][3], s[1][0]), s[1][1]);
    float m3 = fmaxf(fmaxf(s[1][2], s[1][3]), s[2][0]);
    float m4 = fmaxf(fmaxf(s[2][1], s[2][2]), s[2][3]);
    float m5 = fmaxf(fmaxf(s[3][0], s[3][1]), s[3][2]);
    float mloc = fmaxf(fmaxf(fmaxf(m1, m2), fmaxf(m3, m4)), fmaxf(m5, s[3][3]));

    if (!__all(mloc + cb <= m_r + 12.0f)) {   // defer-max (log2 domain)
      float mxrow = fmaxf(mloc, __shfl_xor(mloc, 16));
      mxrow = fmaxf(mxrow, __shfl_xor(mxrow, 32));
      float mnew = fmaxf(m_r, mxrow + cb);
      float alpha = exp2f(m_r - mnew);
      m_r = mnew;
      float a4[4];
#pragma unroll
      for (int r = 0; r < 4; r++) a4[r] = __shfl(alpha, (g << 2) + r);
#pragma unroll
      for (int tt = 0; tt < 4; tt++) {
        f32x4 o = oacc[tt];
        o[0] *= a4[0]; o[1] *= a4[1]; o[2] *= a4[2]; o[3] *= a4[3];
        oacc[tt] = o;
      }
      lacc[0] *= a4[0]; lacc[1] *= a4[1]; lacc[2] *= a4[2]; lacc[3] *= a4[3];
    }

    // P = 2^(s + cb - m), bias (or const) folded into eb
    float eb = cb - m_r;
#pragma unroll
    for (int nt = 0; nt < 4; nt++)
#pragma unroll
      for (int r = 0; r < 4; r++)
        s[nt][r] = __builtin_amdgcn_exp2f(s[nt][r] + eb);

    // pack P -> bf16 pairs, then permlane-swap into PV A-fragments
    unsigned int wpk[4][2];
#pragma unroll
    for (int nt = 0; nt < 4; nt++) {
      wpk[nt][0] = cvtpk(s[nt][0], s[nt][1]);
      wpk[nt][1] = cvtpk(s[nt][2], s[nt][3]);
    }
    u16x8 pa[2];
#pragma unroll
    for (int kk = 0; kk < 2; kk++) {
      unsigned int X0 = wpk[2 * kk][0], Y0 = wpk[2 * kk + 1][0];
      asm volatile("v_permlane32_swap_b32 %0, %1" : "+v"(X0), "+v"(Y0));
      asm volatile("v_permlane16_swap_b32 %0, %1" : "+v"(X0), "+v"(Y0));
      unsigned int X1 = wpk[2 * kk][1], Y1 = wpk[2 * kk + 1][1];
      asm volatile("v_permlane32_swap_b32 %0, %1" : "+v"(X1), "+v"(Y1));
      asm volatile("v_permlane16_swap_b32 %0, %1" : "+v"(X1), "+v"(Y1));
      u32x4 pw = {X0, X1, Y0, Y1};   // words w0,w1,w2,w3
      pa[kk] = __builtin_bit_cast(u16x8, pw);
    }

    // O += P V ; l += P * ones
    __builtin_amdgcn_s_setprio(1);
#pragma unroll
    for (int tt = 0; tt < 4; tt++) {
      int d = tt * 16 + l15;
      int sw = (d & 7) << 4;
      u16x8 vb0 = *(const u16x8*)(vbuf + (d << 7) + ((g << 4) ^ sw));
      u16x8 vb1 = *(const u16x8*)(vbuf + (d << 7) + ((64 + (g << 4)) ^ sw));
      oacc[tt] = MFMA(pa[0], vb0, oacc[tt]);
      oacc[tt] = MFMA(pa[1], vb1, oacc[tt]);
    }
    lacc = MFMA(pa[0], ones, lacc);
    lacc = MFMA(pa[1], ones, lacc);
    __builtin_amdgcn_s_setprio(0);
  };

  STAGE(0, 0);
  STAGE(1, 1);
  __syncthreads();

  for (int it = 0; it < 16; ++it) {
    const int p  = (it & 1) << 1;          // pair being read: bufs p, p+1
    const int sp = ((it + 1) & 1) << 1;    // pair being staged
    if (it < 15) {
      STAGE(2 * it + 2, sp);
      STAGE(2 * it + 3, sp + 1);
    }
    TILE(2 * it, p);
    __builtin_amdgcn_sched_barrier(0);     // keep the two bodies sequential
    TILE(2 * it + 1, p + 1);
    __syncthreads();                       // one barrier per 2 tiles
  }

#pragma unroll
  for (int r = 0; r < 4; r++) {
    float inv = 1.0f / lacc[r];
    size_t rowoff = ((size_t)(b * 2048 + q0 + (g << 2) + r) << 10) + h * 64;
#pragma unroll
    for (int tt = 0; tt < 4; tt++)
      ctx[rowoff + tt * 16 + l15] = f2bf(oacc[tt][r] * inv);
  }
}

// ---------------------------------------------------------------------------
extern "C" void kernel_launch(void* const* d_in, const int* in_sizes, int n_in,
                              void* d_out, int out_size, void* d_ws, size_t ws_size,
                              hipStream_t stream) {
  const float* hs = (const float*)d_in[0];
  const float* wq = (const float*)d_in[1];
  const float* wk = (const float*)d_in[2];
  const float* wv = (const float*)d_in[3];
  const float* wo = (const float*)d_in[4];
  const float* re = (const float*)d_in[5];

  if (ws_size < 50593728u) return;

  char* ws = (char*)d_ws;
  unsigned short* hsb = (unsigned short*)(ws);              // [4096][1024] bf16
  unsigned short* wt  = (unsigned short*)(ws + 8388608);    // [3072][1024] bf16
  unsigned short* wot = (unsigned short*)(ws + 14680064);   // [1024][1024] bf16
  unsigned short* qkv = (unsigned short*)(ws + 16777216);   // q,k [p][s][d]; v^T [p][d][s]
  unsigned short* ctx = (unsigned short*)(ws + 41943040);   // [4096][1024] bf16
  float*          btab = (float*)(ws + 50331648);           // [16][4095] fp32 (x log2e)

  k_prep<<<5376, 256, 0, stream>>>(hs, wq, wk, wv, wo, re, hsb, wt, wot, btab);
  k_gemm<0><<<dim3(24, 32), 256, 0, stream>>>(hsb, wt, qkv, 4096, 3072, 1024);
  k_attn<<<512, 512, 0, stream>>>(qkv, btab, ctx);
  k_gemm<1><<<dim3(8, 32), 256, 0, stream>>>(ctx, wot, d_out, 4096, 1024, 1024);
}

// Round 13
// 121.327 us; speedup vs baseline: 1.5699x; 1.0171x over previous
//
#include <hip/hip_runtime.h>

// ---------------------------------------------------------------------------
// T5Attention forward: out = (softmax(Q K^T + bias) V) Wo
// B=2, S=2048, D=1024, H=16, DK=64, buckets=32, max_dist=128
// bf16 MFMA (16x16x32), fp32 accumulate.
// r13 = r12 (passing, 123.4us) with k_attn VALU trims ONLY:
//   - eb = cb - m_r folded into QK MFMA C-input (saves 16 v_add/tile);
//     m_r init 0.0 (scores bounded, defer-max renormalizes; exact math)
//   - row max via v_max3_f32 (15 fmax -> 8 ops)
// Prep + GEMMs + sync structure identical to r12.
// ---------------------------------------------------------------------------

typedef __attribute__((ext_vector_type(8)))  unsigned short u16x8;
typedef __attribute__((ext_vector_type(4)))  unsigned short u16x4;
typedef __attribute__((ext_vector_type(8)))  __bf16         bf16x8;
typedef __attribute__((ext_vector_type(4)))  float          f32x4;
typedef __attribute__((ext_vector_type(4)))  unsigned int   u32x4;

#define GLOBAL_AS __attribute__((address_space(1)))
#define LDS_AS    __attribute__((address_space(3)))

static __device__ inline f32x4 MFMA(u16x8 a, u16x8 b, f32x4 c) {
  return __builtin_amdgcn_mfma_f32_16x16x32_bf16(
      __builtin_bit_cast(bf16x8, a), __builtin_bit_cast(bf16x8, b), c, 0, 0, 0);
}

static __device__ inline void gload16(const void* g, void* l) {
  __builtin_amdgcn_global_load_lds((const GLOBAL_AS unsigned int*)g,
                                   (LDS_AS unsigned int*)l, 16, 0, 0);
}

// float -> bf16 bits, round-to-nearest-even
static __device__ inline unsigned short f2bf(float x) {
  unsigned int u = __builtin_bit_cast(unsigned int, x);
  u = (u + 0x7FFFu + ((u >> 16) & 1u)) >> 16;
  return (unsigned short)u;
}

// packed f32x2 -> bf16x2, one instruction
static __device__ inline unsigned int cvtpk(float lo, float hi) {
  unsigned int r;
  asm volatile("v_cvt_pk_bf16_f32 %0, %1, %2" : "=v"(r) : "v"(lo), "v"(hi));
  return r;
}

// 3-input max, one instruction
static __device__ inline float max3f(float a, float b, float c) {
  float r;
  asm volatile("v_max3_f32 %0, %1, %2, %3" : "=v"(r) : "v"(a), "v"(b), "v"(c));
  return r;
}

#define L2E 1.4426950408889634f

// ---------------------------------------------------------------------------
// fused prep: blocks [0,4096) cvt hs; [4096,5120) transpose 4 weights;
// [5120,5376) bias table. All independent.
__global__ __launch_bounds__(256) void k_prep(const float* __restrict__ hs,
                                              const float* __restrict__ wq,
                                              const float* __restrict__ wk,
                                              const float* __restrict__ wv,
                                              const float* __restrict__ wo,
                                              const float* __restrict__ re,
                                              unsigned short* __restrict__ hsb,
                                              unsigned short* __restrict__ wt,
                                              unsigned short* __restrict__ wot,
                                              float* __restrict__ btab) {
  __shared__ float tile[64][65];
  const int bid = blockIdx.x;
  const int t = threadIdx.x;

  if (bid < 4096) {              // ---- fp32 -> bf16 convert of hidden_states
    int i = bid * 256 + t;
    float4 v = *(const float4*)(hs + (size_t)i * 4);
    u16x4 o;
    o[0] = f2bf(v.x); o[1] = f2bf(v.y); o[2] = f2bf(v.z); o[3] = f2bf(v.w);
    *(u16x4*)(hsb + (size_t)i * 4) = o;
  } else if (bid < 5120) {       // ---- transpose+convert one 64x64 tile
    int sub = bid - 4096;
    int which = sub >> 8;        // 0=wq 1=wk 2=wv 3=wo
    int sb = sub & 255;
    int n0 = (sb & 15) << 6, k0 = (sb >> 4) << 6;
    const float* src = which == 0 ? wq : which == 1 ? wk : which == 2 ? wv : wo;
    unsigned short* dst = which == 0 ? wt
                        : which == 1 ? wt + 1048576
                        : which == 2 ? wt + 2097152 : wot;
    const int K = 1024, N = 1024;
    int rr = t >> 4, cc = (t & 15) << 2;
#pragma unroll
    for (int j = 0; j < 4; j++) {
      float4 v = *(const float4*)(src + (size_t)(k0 + rr + j * 16) * N + n0 + cc);
      tile[rr + j * 16][cc + 0] = v.x;
      tile[rr + j * 16][cc + 1] = v.y;
      tile[rr + j * 16][cc + 2] = v.z;
      tile[rr + j * 16][cc + 3] = v.w;
    }
    __syncthreads();
#pragma unroll
    for (int j = 0; j < 4; j++) {
      int n = rr + j * 16;
      u16x4 o;
      o[0] = f2bf(tile[cc + 0][n]);
      o[1] = f2bf(tile[cc + 1][n]);
      o[2] = f2bf(tile[cc + 2][n]);
      o[3] = f2bf(tile[cc + 3][n]);
      *(u16x4*)(dst + (size_t)(n0 + n) * K + k0 + cc) = o;
    }
  } else {                       // ---- bias table (pre-scaled by log2e)
    int i = (bid - 5120) * 256 + t;
    if (i < 16 * 4095) {
      int h = i / 4095;
      int rp = i % 4095 - 2047;
      int rb = rp > 0 ? 16 : 0;
      int arp = rp < 0 ? -rp : rp;
      int v;
      if (arp < 8) {
        v = arp;
      } else {
        float tt = logf((float)arp * 0.125f);
        tt = tt / 2.772588722239781f;
        tt = tt * 8.0f;
        v = 8 + (int)tt;
        if (v > 15) v = 15;
      }
      btab[i] = re[(rb + v) * 16 + h] * L2E;
    }
  }
}

// ---------------------------------------------------------------------------
// GEMM: C[M,N] = A[M,K](bf16) * Bt[N,K](bf16, pre-transposed)
// EPI=0: scatter into qkv planes; Q scaled by log2e; V written TRANSPOSED
//        ([plane][d][s]). EPI=1: fp32 row-major out.
template <int EPI>
__global__ __launch_bounds__(256) void k_gemm(const unsigned short* __restrict__ A,
                                              const unsigned short* __restrict__ Bt,
                                              void* __restrict__ outp,
                                              int M, int N, int K) {
  __shared__ __attribute__((aligned(16))) char smem[32768];
  const int tid = threadIdx.x;
  const int lane = tid & 63, w = tid >> 6;
  const int l15 = lane & 15, g = lane >> 4;
  const int wr = w >> 1, wc = w & 1;
  const int bm0 = blockIdx.y << 7, bn0 = blockIdx.x << 7;

  const char* Ag = (const char*)A + (size_t)bm0 * K * 2;
  const char* Bg = (const char*)Bt + (size_t)bn0 * K * 2;

  f32x4 acc[4][4];
#pragma unroll
  for (int i = 0; i < 4; i++)
#pragma unroll
    for (int j = 0; j < 4; j++) acc[i][j] = (f32x4)0.0f;

  const int rowA = wr * 64 + l15;
  const int rowB = wc * 64 + l15;
  const int swz = (l15 & 7) << 4;

  for (int kt = 0; kt < K; kt += 64) {
#pragma unroll
    for (int j = 0; j < 4; j++) {
      int idx = ((j * 4 + w) << 10) + (lane << 4);
      int row = idx >> 7;
      int gs = (idx >> 4) & 7;
      size_t co = (size_t)row * (K * 2) + kt * 2 + ((gs ^ (row & 7)) << 4);
      gload16(Ag + co, smem + ((j * 4 + w) << 10));
      gload16(Bg + co, smem + 16384 + ((j * 4 + w) << 10));
    }
    __syncthreads();
#pragma unroll
    for (int kk = 0; kk < 2; kk++) {
      const int cp = ((kk << 6) + (g << 4)) ^ swz;
      u16x8 af[4], bfv[4];
#pragma unroll
      for (int mt = 0; mt < 4; mt++)
        af[mt] = *(const u16x8*)(smem + ((rowA + mt * 16) << 7) + cp);
#pragma unroll
      for (int nt = 0; nt < 4; nt++)
        bfv[nt] = *(const u16x8*)(smem + 16384 + ((rowB + nt * 16) << 7) + cp);
#pragma unroll
      for (int mt = 0; mt < 4; mt++)
#pragma unroll
        for (int nt = 0; nt < 4; nt++)
          acc[mt][nt] = MFMA(af[mt], bfv[nt], acc[mt][nt]);
    }
    __syncthreads();
  }

#pragma unroll
  for (int mt = 0; mt < 4; mt++) {
#pragma unroll
    for (int nt = 0; nt < 4; nt++) {
#pragma unroll
      for (int r = 0; r < 4; r++) {
        int m = bm0 + wr * 64 + mt * 16 + g * 4 + r;
        int n = bn0 + wc * 64 + nt * 16 + l15;
        float val = acc[mt][nt][r];
        if (EPI == 0) {
          int which = n >> 10;
          int hh = (n >> 6) & 15;
          int d = n & 63;
          int bb = m >> 11, s = m & 2047;
          int plane = bb * 16 + hh;
          unsigned short* o = (unsigned short*)outp;
          if (which == 0) {        // Q, pre-scaled by log2e
            o[(size_t)plane * 131072 + (size_t)s * 64 + d] = f2bf(val * L2E);
          } else if (which == 1) { // K
            o[4194304 + (size_t)plane * 131072 + (size_t)s * 64 + d] = f2bf(val);
          } else {                 // V^T: [plane][d][s]
            o[8388608 + (size_t)plane * 131072 + (size_t)d * 2048 + s] = f2bf(val);
          }
        } else {
          ((float*)outp)[(size_t)m * N + n] = val;
        }
      }
    }
  }
}

// ---------------------------------------------------------------------------
// Flash attention — 8 waves/block, grid 512. r12 structure (4 buffers,
// 2 sequential tiles per barrier). eb folded into MFMA C-init; max3 row-max.
__global__ __launch_bounds__(512, 6) void k_attn(const unsigned short* __restrict__ qkv,
                                                 const float* __restrict__ btab,
                                                 unsigned short* __restrict__ ctx) {
  __shared__ __attribute__((aligned(16))) char smem[65536]; // 4 x (K 8K + V 8K)
  const int tid = threadIdx.x;
  const int lane = tid & 63, w = tid >> 6;      // w in [0,8)
  const int l15 = lane & 15, g = lane >> 4;

  // chunked XCD map: each XCD gets 4 consecutive planes
  const int wg = ((blockIdx.x & 7) << 6) + (blockIdx.x >> 3);
  const int plane = wg >> 4, qb = wg & 15;
  const int h = plane & 15, b = plane >> 4;
  const int q0 = (qb << 7) + (w << 4);          // block: 128 q rows, wave: 16

  const unsigned short* Qp = qkv + (size_t)plane * 131072;
  const unsigned short* Kp = qkv + 4194304 + (size_t)plane * 131072;
  const unsigned short* Vt = qkv + 8388608 + (size_t)plane * 131072;

  u16x8 qa[2];
#pragma unroll
  for (int kk = 0; kk < 2; kk++)
    qa[kk] = *(const u16x8*)(Qp + (size_t)(q0 + l15) * 64 + kk * 32 + g * 8);

  // m_r starts at 0 (NOT -inf): scores bounded (|s|<~55 in log2 domain), so
  // 2^s is finite in fp32; defer-max renormalizes. Exact softmax shift-invar.
  float m_r = 0.0f;
  f32x4 oacc[4], lacc;
#pragma unroll
  for (int t = 0; t < 4; t++) oacc[t] = (f32x4)0.0f;
  lacc = (f32x4)0.0f;

  const float* brow = btab + h * 4095 + 2047 - q0;
  const float cpos = btab[h * 4095 + 2047 + 1024];
  const float cneg = btab[h * 4095 + 2047 - 1024];

  u16x8 ones;
  {
    u32x4 ov = {0x3F803F80u, 0x3F803F80u, 0x3F803F80u, 0x3F803F80u};
    ones = __builtin_bit_cast(u16x8, ov);
  }

  // staging source addrs (pre-swizzled, linear LDS dest); 8 waves x 1 row-band
  const int srow = (w << 3) + (lane >> 3);   // 0..63
  const int soff = ((lane & 7) ^ (srow & 7)) << 4;
  const char* Ksrc = (const char*)Kp + (size_t)srow * 128 + soff;
  const char* Vsrc = (const char*)Vt + (size_t)srow * 4096 + soff;

  auto STAGE = [&](int t, int bsel) {
    char* sb = smem + (bsel << 14) + (w << 10);
    gload16(Ksrc + (size_t)t * 8192, sb);            // K rows w*8..w*8+7
    gload16(Vsrc + (size_t)t * 128, sb + 8192);      // V^T d rows w*8..w*8+7
  };

  // ---- one 64-key tile ----
  auto TILE = [&](int t, int bsel) {
    const char* kb = smem + (bsel << 14);
    const char* vbuf = kb + 8192;
    const int kv = t << 6;

    // bias classification BEFORE MFMA; eb folded into accumulator init
    int delta_t = kv - q0;
    bool far = (delta_t >= 112 || delta_t <= -160);
    float cb = far ? (delta_t > 0 ? cpos : cneg) : 0.0f;
    float ebi = cb - m_r;
    f32x4 z0 = {ebi, ebi, ebi, ebi};

    // S^T = K Q^T + eb : lane holds s for q = q0 + l15, 16 keys
    f32x4 s[4];
    __builtin_amdgcn_s_setprio(1);
#pragma unroll
    for (int nt = 0; nt < 4; nt++) {
      int keyr = nt * 16 + l15;
      int sw = (keyr & 7) << 4;
      u16x8 kb0 = *(const u16x8*)(kb + (keyr << 7) + ((g << 4) ^ sw));
      u16x8 kb1 = *(const u16x8*)(kb + (keyr << 7) + ((64 + (g << 4)) ^ sw));
      f32x4 z = MFMA(kb0, qa[0], z0);
      z = MFMA(kb1, qa[1], z);
      s[nt] = z;
    }
    __builtin_amdgcn_s_setprio(0);

    // near tiles: add per-element bias (log2 domain)
    if (!far) {
      const float* bp = brow + kv + (g << 2) - l15;
#pragma unroll
      for (int nt = 0; nt < 4; nt++)
#pragma unroll
        for (int r = 0; r < 4; r++) s[nt][r] += bp[nt * 16 + r];
    }

    // row max via max3 (2 parallel chains)
    float ma = max3f(s[0][0], s[0][1], s[0][2]);
    ma = max3f(ma, s[0][3], s[1][0]);
    ma = max3f(ma, s[1][1], s[1][2]);
    ma = fmaxf(ma, s[1][3]);
    float mb = max3f(s[2][0], s[2][1], s[2][2]);
    mb = max3f(mb, s[2][3], s[3][0]);
    mb = max3f(mb, s[3][1], s[3][2]);
    mb = fmaxf(mb, s[3][3]);
    float mloc = fmaxf(ma, mb);

    // defer-max: s is already (true - m_r); rescale only if growth > 12
    if (!__all(mloc <= 12.0f)) {
      float mxrow = fmaxf(mloc, __shfl_xor(mloc, 16));
      mxrow = fmaxf(mxrow, __shfl_xor(mxrow, 32));
      float dlt = fmaxf(mxrow, 0.0f);      // per-row, uniform across g
      m_r += dlt;
      float alpha = exp2f(-dlt);
#pragma unroll
      for (int nt = 0; nt < 4; nt++)
#pragma unroll
        for (int r = 0; r < 4; r++) s[nt][r] -= dlt;
      float a4[4];
#pragma unroll
      for (int r = 0; r < 4; r++) a4[r] = __shfl(alpha, (g << 2) + r);
#pragma unroll
      for (int tt = 0; tt < 4; tt++) {
        f32x4 o = oacc[tt];
        o[0] *= a4[0]; o[1] *= a4[1]; o[2] *= a4[2]; o[3] *= a4[3];
        oacc[tt] = o;
      }
      lacc[0] *= a4[0]; lacc[1] *= a4[1]; lacc[2] *= a4[2]; lacc[3] *= a4[3];
    }

    // P = 2^s directly; pack to bf16 pairs
    unsigned int wpk[4][2];
#pragma unroll
    for (int nt = 0; nt < 4; nt++) {
#pragma unroll
      for (int r = 0; r < 4; r++)
        s[nt][r] = __builtin_amdgcn_exp2f(s[nt][r]);
      wpk[nt][0] = cvtpk(s[nt][0], s[nt][1]);
      wpk[nt][1] = cvtpk(s[nt][2], s[nt][3]);
    }
    u16x8 pa[2];
#pragma unroll
    for (int kk = 0; kk < 2; kk++) {
      unsigned int X0 = wpk[2 * kk][0], Y0 = wpk[2 * kk + 1][0];
      asm volatile("v_permlane32_swap_b32 %0, %1" : "+v"(X0), "+v"(Y0));
      asm volatile("v_permlane16_swap_b32 %0, %1" : "+v"(X0), "+v"(Y0));
      unsigned int X1 = wpk[2 * kk][1], Y1 = wpk[2 * kk + 1][1];
      asm volatile("v_permlane32_swap_b32 %0, %1" : "+v"(X1), "+v"(Y1));
      asm volatile("v_permlane16_swap_b32 %0, %1" : "+v"(X1), "+v"(Y1));
      u32x4 pw = {X0, X1, Y0, Y1};   // words w0,w1,w2,w3
      pa[kk] = __builtin_bit_cast(u16x8, pw);
    }

    // O += P V ; l += P * ones
    __builtin_amdgcn_s_setprio(1);
#pragma unroll
    for (int tt = 0; tt < 4; tt++) {
      int d = tt * 16 + l15;
      int sw = (d & 7) << 4;
      u16x8 vb0 = *(const u16x8*)(vbuf + (d << 7) + ((g << 4) ^ sw));
      u16x8 vb1 = *(const u16x8*)(vbuf + (d << 7) + ((64 + (g << 4)) ^ sw));
      oacc[tt] = MFMA(pa[0], vb0, oacc[tt]);
      oacc[tt] = MFMA(pa[1], vb1, oacc[tt]);
    }
    lacc = MFMA(pa[0], ones, lacc);
    lacc = MFMA(pa[1], ones, lacc);
    __builtin_amdgcn_s_setprio(0);
  };

  STAGE(0, 0);
  STAGE(1, 1);
  __syncthreads();

  for (int it = 0; it < 16; ++it) {
    const int p  = (it & 1) << 1;          // pair being read: bufs p, p+1
    const int sp = ((it + 1) & 1) << 1;    // pair being staged
    if (it < 15) {
      STAGE(2 * it + 2, sp);
      STAGE(2 * it + 3, sp + 1);
    }
    TILE(2 * it, p);
    __builtin_amdgcn_sched_barrier(0);     // keep the two bodies sequential
    TILE(2 * it + 1, p + 1);
    __syncthreads();                       // one barrier per 2 tiles
  }

#pragma unroll
  for (int r = 0; r < 4; r++) {
    float inv = 1.0f / lacc[r];
    size_t rowoff = ((size_t)(b * 2048 + q0 + (g << 2) + r) << 10) + h * 64;
#pragma unroll
    for (int tt = 0; tt < 4; tt++)
      ctx[rowoff + tt * 16 + l15] = f2bf(oacc[tt][r] * inv);
  }
}

// ---------------------------------------------------------------------------
extern "C" void kernel_launch(void* const* d_in, const int* in_sizes, int n_in,
                              void* d_out, int out_size, void* d_ws, size_t ws_size,
                              hipStream_t stream) {
  const float* hs = (const float*)d_in[0];
  const float* wq = (const float*)d_in[1];
  const float* wk = (const float*)d_in[2];
  const float* wv = (const float*)d_in[3];
  const float* wo = (const float*)d_in[4];
  const float* re = (const float*)d_in[5];

  if (ws_size < 50593728u) return;

  char* ws = (char*)d_ws;
  unsigned short* hsb = (unsigned short*)(ws);              // [4096][1024] bf16
  unsigned short* wt  = (unsigned short*)(ws + 8388608);    // [3072][1024] bf16
  unsigned short* wot = (unsigned short*)(ws + 14680064);   // [1024][1024] bf16
  unsigned short* qkv = (unsigned short*)(ws + 16777216);   // q,k [p][s][d]; v^T [p][d][s]
  unsigned short* ctx = (unsigned short*)(ws + 41943040);   // [4096][1024] bf16
  float*          btab = (float*)(ws + 50331648);           // [16][4095] fp32 (x log2e)

  k_prep<<<5376, 256, 0, stream>>>(hs, wq, wk, wv, wo, re, hsb, wt, wot, btab);
  k_gemm<0><<<dim3(24, 32), 256, 0, stream>>>(hsb, wt, qkv, 4096, 3072, 1024);
  k_attn<<<512, 512, 0, stream>>>(qkv, btab, ctx);
  k_gemm<1><<<dim3(8, 32), 256, 0, stream>>>(ctx, wot, d_out, 4096, 1024, 1024);
}